// Round 6
// baseline (464.937 us; speedup 1.0000x reference)
//
#include <hip/hip_runtime.h>
#include <hip/hip_bf16.h>
#include <hip/hip_fp16.h>

namespace {

constexpr int N    = 65536;
constexpr int E    = 1048576;
constexpr int N2   = 2 * N;      // both sides concatenated
constexpr int B    = 128;
constexpr int NPG  = 512;
constexpr int IN   = 128;
constexpr int H    = 64;
constexpr int BINS = 16;
constexpr int FIN  = 2 * H + BINS + 3;  // 147
// CSR bucket scheme: 512 buckets of 256 dsts; 512 slices of 4096 edges.
constexpr int NBUCKET = 512;
constexpr int NSLICE  = 512;
constexpr int SLICE_E = 4096;

// ---------------- P1 (blocks 0..511): bucket histogram per slice, LDS only.
// ---------------- blocks 512..4607: y = x @ W1 -> fp16 (independent work, co-scheduled).

__global__ __launch_bounds__(256) void k_p1_xw(const int* __restrict__ dst1, const int* __restrict__ dst2,
                                               int* __restrict__ bcnt,
                                               const float* __restrict__ x1, const float* __restrict__ x2,
                                               const float* __restrict__ W, __half* __restrict__ y) {
  __shared__ float sW[IN * H];                     // 32 KB
  __shared__ __align__(16) float sx[4][IN][8];     // 16 KB
  __shared__ int hist[NBUCKET];                    // 2 KB
  int b = blockIdx.x, tid = threadIdx.x;
  if (b < NSLICE) {
    hist[tid] = 0;
    hist[tid + 256] = 0;
    __syncthreads();
    const int* d = (b < 256) ? dst1 : dst2;
    int ebase = (b & 255) * SLICE_E;
    int boff = (b < 256) ? 0 : 256;  // side2 dst+N -> bucket+256 (N = 256*256)
    for (int i = tid; i < SLICE_E; i += 256) atomicAdd(&hist[boff + (d[ebase + i] >> 8)], 1);
    __syncthreads();
    for (int k = tid; k < NBUCKET; k += 256) bcnt[b * NBUCKET + k] = hist[k];
  } else {
    int bx = b - NSLICE;
    int lane = tid & 63, sub = tid >> 6;
    for (int i = tid; i < IN * H; i += 256) sW[i] = W[i];
    __syncthreads();
    int nbase = bx * 32 + sub * 8;
    const float* xp = (nbase < N) ? (x1 + (size_t)nbase * IN) : (x2 + (size_t)(nbase - N) * IN);
#pragma unroll
    for (int nd = 0; nd < 8; ++nd) {
      const float* xr = xp + (size_t)nd * IN;
      sx[sub][lane][nd]      = xr[lane];
      sx[sub][lane + 64][nd] = xr[lane + 64];
    }
    // same-wave LDS producer/consumer: no barrier needed
    float acc[8];
#pragma unroll
    for (int nd = 0; nd < 8; ++nd) acc[nd] = 0.f;
    for (int k = 0; k < IN; ++k) {
      float wv = sW[k * H + lane];
      const float* p = &sx[sub][k][0];
      float4 lo = *(const float4*)(p);
      float4 hi = *(const float4*)(p + 4);
      acc[0] = fmaf(lo.x, wv, acc[0]); acc[1] = fmaf(lo.y, wv, acc[1]);
      acc[2] = fmaf(lo.z, wv, acc[2]); acc[3] = fmaf(lo.w, wv, acc[3]);
      acc[4] = fmaf(hi.x, wv, acc[4]); acc[5] = fmaf(hi.y, wv, acc[5]);
      acc[6] = fmaf(hi.z, wv, acc[6]); acc[7] = fmaf(hi.w, wv, acc[7]);
    }
#pragma unroll
    for (int nd = 0; nd < 8; ++nd) y[(size_t)(nbase + nd) * H + lane] = __float2half(acc[nd]);
  }
}

// P2: per-bucket exclusive scan across slices. boffs[bucket][slice]; tot[bucket].
__global__ __launch_bounds__(256) void k_scanrows(const int* __restrict__ bcnt, int* __restrict__ boffs,
                                                  int* __restrict__ tot) {
  __shared__ int s[NSLICE];
  int b = blockIdx.x, t = threadIdx.x;
  int v0 = bcnt[t * NBUCKET + b], v1 = bcnt[(t + 256) * NBUCKET + b];
  s[t] = v0;
  s[t + 256] = v1;
  __syncthreads();
  for (int d = 1; d < NSLICE; d <<= 1) {
    int a0 = (t >= d) ? s[t - d] : 0;
    int a1 = (t + 256 >= d) ? s[t + 256 - d] : 0;
    __syncthreads();
    s[t] += a0;
    s[t + 256] += a1;
    __syncthreads();
  }
  boffs[b * NSLICE + t] = s[t] - v0;
  boffs[b * NSLICE + t + 256] = s[t + 256] - v1;
  if (t == 255) tot[b] = s[NSLICE - 1];
}

// P5: scatter edges into bucket-grouped ebuf, packed (dstLow8 << 17) | src.
// LDS cursors only; bucket base scan recomputed in LDS (no extra launch).
__global__ __launch_bounds__(256) void k_p5(const int* __restrict__ src1, const int* __restrict__ dst1,
                                            const int* __restrict__ src2, const int* __restrict__ dst2,
                                            const int* __restrict__ boffs, const int* __restrict__ tot,
                                            int* __restrict__ ebuf) {
  __shared__ int stot[NBUCKET];
  __shared__ int sofs[NBUCKET];
  __shared__ int cur[NBUCKET];
  int b = blockIdx.x, tid = threadIdx.x;
  int v0 = tot[tid], v1 = tot[tid + 256];
  stot[tid] = v0;
  stot[tid + 256] = v1;
  __syncthreads();
  for (int d = 1; d < NBUCKET; d <<= 1) {
    int a0 = (tid >= d) ? stot[tid - d] : 0;
    int a1 = (tid + 256 >= d) ? stot[tid + 256 - d] : 0;
    __syncthreads();
    stot[tid] += a0;
    stot[tid + 256] += a1;
    __syncthreads();
  }
  sofs[tid]       = stot[tid] - v0 + boffs[tid * NSLICE + b];
  sofs[tid + 256] = stot[tid + 256] - v1 + boffs[(tid + 256) * NSLICE + b];
  cur[tid] = 0;
  cur[tid + 256] = 0;
  __syncthreads();
  const int* sr = (b < 256) ? src1 : src2;
  const int* d  = (b < 256) ? dst1 : dst2;
  int ebase = (b & 255) * SLICE_E;
  int off = (b < 256) ? 0 : N;
  int boff2 = (b < 256) ? 0 : 256;
  for (int i = tid; i < SLICE_E; i += 256) {
    int dd = d[ebase + i];
    int sv = off + sr[ebase + i];
    int bucket = boff2 + (dd >> 8);
    int r = atomicAdd(&cur[bucket], 1);
    ebuf[sofs[bucket] + r] = ((dd & 255) << 17) | sv;
  }
}

// P6: per-bucket CSR finalize (contiguous edge segment). LDS count+scan+scatter.
__global__ __launch_bounds__(256) void k_p6(const int* __restrict__ ebuf, const int* __restrict__ tot,
                                            int* __restrict__ rowptr, int* __restrict__ col) {
  __shared__ int stot[NBUCKET];
  __shared__ int c256[256];
  __shared__ int lofs[256];
  int b = blockIdx.x, t = threadIdx.x;
  {
    int v0 = tot[t], v1 = tot[t + 256];
    stot[t] = v0;
    stot[t + 256] = v1;
    __syncthreads();
    for (int d = 1; d < NBUCKET; d <<= 1) {
      int a0 = (t >= d) ? stot[t - d] : 0;
      int a1 = (t + 256 >= d) ? stot[t + 256 - d] : 0;
      __syncthreads();
      stot[t] += a0;
      stot[t + 256] += a1;
      __syncthreads();
    }
  }
  int e0 = (b == 0) ? 0 : stot[b - 1];
  int e1 = stot[b];
  c256[t] = 0;
  __syncthreads();
  for (int i = e0 + t; i < e1; i += 256) atomicAdd(&c256[(ebuf[i] >> 17) & 255], 1);
  __syncthreads();
  int v = c256[t];
  lofs[t] = v;
  __syncthreads();
  for (int d = 1; d < 256; d <<= 1) {
    int a = (t >= d) ? lofs[t - d] : 0;
    __syncthreads();
    lofs[t] += a;
    __syncthreads();
  }
  int excl = lofs[t] - v;
  rowptr[b * 256 + t] = e0 + excl;
  if (b == 0 && t == 0) rowptr[N2] = 2 * E;
  c256[t] = 0;
  lofs[t] = excl;
  __syncthreads();
  for (int i = e0 + t; i < e1; i += 256) {
    int pk = ebuf[i];
    int dl = (pk >> 17) & 255;
    int r = atomicAdd(&c256[dl], 1);
    col[e0 + lofs[dl] + r] = pk & 0x1FFFF;
  }
}

// ---------------- fused gather + dense ----------------
// gather: t[n] = relu(in[n] + sum_{j->n} in[j] + b0)   (fp16 rows, f32 accumulate)

__device__ __forceinline__ float gather_node(const __half* __restrict__ in, const int* __restrict__ rowptr,
                                             const int* __restrict__ col, int n, int lane, float bias0) {
  int p0 = rowptr[n], p1 = rowptr[n + 1];
  float a = __half2float(in[(size_t)n * H + lane]) + bias0;
  int p = p0;
  for (; p + 16 <= p1; p += 16) {
    int myc = (lane < 16) ? col[p + lane] : 0;
    float v[16];
#pragma unroll
    for (int i = 0; i < 16; ++i) {
      int c = __shfl(myc, i, 64);
      v[i] = __half2float(in[(size_t)c * H + lane]);
    }
#pragma unroll
    for (int i = 0; i < 16; ++i) a += v[i];
  }
  if (p < p1) {
    int cnt = p1 - p;
    int myc = (lane < 16 && p + lane < p1) ? col[p + lane] : 0;
#pragma unroll
    for (int i = 0; i < 16; ++i) {
      if (i < cnt) {
        int c = __shfl(myc, i, 64);
        a += __half2float(in[(size_t)c * H + lane]);
      }
    }
  }
  return fmaxf(a, 0.f);
}

__device__ __forceinline__ void fma8(float (&acc)[8], const float* p, float wv) {
  float4 lo = *(const float4*)(p);
  float4 hi = *(const float4*)(p + 4);
  acc[0] = fmaf(lo.x, wv, acc[0]);
  acc[1] = fmaf(lo.y, wv, acc[1]);
  acc[2] = fmaf(lo.z, wv, acc[2]);
  acc[3] = fmaf(lo.w, wv, acc[3]);
  acc[4] = fmaf(hi.x, wv, acc[4]);
  acc[5] = fmaf(hi.y, wv, acc[5]);
  acc[6] = fmaf(hi.z, wv, acc[6]);
  acc[7] = fmaf(hi.w, wv, acc[7]);
}

// layer1 tail fused: t = gather(in); z = (relu(t@Wa + ba)) @ Wb -> fp16
__global__ __launch_bounds__(256) void k_gmid(const __half* __restrict__ in, const int* __restrict__ rowptr,
                                              const int* __restrict__ col, const float* __restrict__ b0v,
                                              const float* __restrict__ Wa, const float* __restrict__ ba,
                                              const float* __restrict__ Wb, __half* __restrict__ out) {
  __shared__ float sWa[H * H];                     // 16 KB
  __shared__ float sWb[H * H];                     // 16 KB
  __shared__ __align__(16) float st[4][H][8];      // 8 KB
  int tid = threadIdx.x, lane = tid & 63, sub = tid >> 6;
  for (int i = tid; i < H * H; i += 256) sWa[i] = Wa[i];
  for (int i = tid; i < H * H; i += 256) sWb[i] = Wb[i];
  float bias0 = b0v[lane], biasA = ba[lane];
  __syncthreads();
  int nbase = blockIdx.x * 32 + sub * 8;
#pragma unroll
  for (int nd = 0; nd < 8; ++nd)
    st[sub][lane][nd] = gather_node(in, rowptr, col, nbase + nd, lane, bias0);
  // same-wave LDS producer/consumer: no barrier needed
  float acc[8];
#pragma unroll
  for (int nd = 0; nd < 8; ++nd) acc[nd] = biasA;
  for (int k = 0; k < H; ++k) fma8(acc, &st[sub][k][0], sWa[k * H + lane]);
#pragma unroll
  for (int nd = 0; nd < 8; ++nd) st[sub][lane][nd] = fmaxf(acc[nd], 0.f);
  float acc2[8];
#pragma unroll
  for (int nd = 0; nd < 8; ++nd) acc2[nd] = 0.f;
  for (int k = 0; k < H; ++k) fma8(acc2, &st[sub][k][0], sWb[k * H + lane]);
#pragma unroll
  for (int nd = 0; nd < 8; ++nd) out[(size_t)(nbase + nd) * H + lane] = __float2half(acc2[nd]);
}

// layer2 tail fused: t2 = gather(in); h = relu(t2@Wa + ba); write L2-normalized h (f32) + pool partials.
__global__ __launch_bounds__(256) void k_glast(const __half* __restrict__ in, const int* __restrict__ rowptr,
                                               const int* __restrict__ col, const float* __restrict__ b0v,
                                               const float* __restrict__ Wa, const float* __restrict__ ba,
                                               float* __restrict__ outn, float* __restrict__ pg) {
  __shared__ float sWa[H * H];                     // 16 KB
  __shared__ __align__(16) float st[4][H][8];      // 8 KB
  __shared__ float sacc[4][64];
  int tid = threadIdx.x, lane = tid & 63, sub = tid >> 6;
  for (int i = tid; i < H * H; i += 256) sWa[i] = Wa[i];
  float bias0 = b0v[lane], biasA = ba[lane];
  __syncthreads();
  int nbase = blockIdx.x * 32 + sub * 8;
#pragma unroll
  for (int nd = 0; nd < 8; ++nd)
    st[sub][lane][nd] = gather_node(in, rowptr, col, nbase + nd, lane, bias0);
  float acc[8];
#pragma unroll
  for (int nd = 0; nd < 8; ++nd) acc[nd] = biasA;
  for (int k = 0; k < H; ++k) fma8(acc, &st[sub][k][0], sWa[k * H + lane]);
  float psum = 0.f;
#pragma unroll
  for (int nd = 0; nd < 8; ++nd) {
    float h = fmaxf(acc[nd], 0.f);
    psum += h;
    float ss = h * h;
#pragma unroll
    for (int d = 1; d < 64; d <<= 1) ss += __shfl_xor(ss, d, 64);
    outn[(size_t)(nbase + nd) * H + lane] = h / fmaxf(sqrtf(ss), 1e-12f);
  }
  sacc[sub][lane] = psum;
  __syncthreads();
  if (sub == 0) pg[blockIdx.x * 64 + lane] = sacc[0][lane] + sacc[1][lane] + sacc[2][lane] + sacc[3][lane];
}

// ---------------- fused sim + hist + stats (float4 LDS, XOR swizzle) ----------------
__global__ __launch_bounds__(256, 3) void k_sim(const float* __restrict__ Hn, float* __restrict__ psum,
                                                float* __restrict__ psumsq, float* __restrict__ pmax,
                                                int* __restrict__ phist) {
  __shared__ float4 s1[64 * 16];   // 16 KB
  __shared__ float4 s2[128 * 16];  // 32 KB
  __shared__ int shist[64 * 17];   // 4.25 KB, 64 replicas stride 17
  __shared__ float sfin[4][4];
  int tid = threadIdx.x;
  int g = blockIdx.x >> 3, rt = blockIdx.x & 7;
  for (int i = tid; i < 64 * 17; i += 256) shist[i] = 0;
  const float4* b1p = (const float4*)(Hn + ((size_t)g * NPG + rt * 64) * H);
  for (int i = tid; i < 1024; i += 256) {
    int row = i >> 4, k4 = i & 15;
    s1[(row << 4) | (k4 ^ (row & 15))] = b1p[i];
  }
  int ty = tid >> 4, tx = tid & 15;
  int rep = (tid & 63) * 17;
  float lmax = -2.f, lsum = 0.f, lsumsq = 0.f;
  const float* H2 = Hn + (size_t)N * H;
  for (int ch = 0; ch < 4; ++ch) {
    __syncthreads();
    const float4* b2p = (const float4*)(H2 + ((size_t)g * NPG + ch * 128) * H);
    for (int i = tid; i < 2048; i += 256) {
      int row = i >> 4, k4 = i & 15;
      s2[(row << 4) | (k4 ^ (row & 15))] = b2p[i];
    }
    __syncthreads();
    float acc[4][8];
#pragma unroll
    for (int i = 0; i < 4; ++i)
#pragma unroll
      for (int j = 0; j < 8; ++j) acc[i][j] = 0.f;
#pragma unroll 2
    for (int k4 = 0; k4 < 16; ++k4) {
      int ka = k4 ^ ty, kb = k4 ^ tx;
      float4 av[4], bv[8];
#pragma unroll
      for (int i = 0; i < 4; ++i) av[i] = s1[((ty + 16 * i) << 4) | ka];
#pragma unroll
      for (int j = 0; j < 8; ++j) bv[j] = s2[((tx + 16 * j) << 4) | kb];
#pragma unroll
      for (int i = 0; i < 4; ++i)
#pragma unroll
        for (int j = 0; j < 8; ++j) {
          acc[i][j] = fmaf(av[i].x, bv[j].x, acc[i][j]);
          acc[i][j] = fmaf(av[i].y, bv[j].y, acc[i][j]);
          acc[i][j] = fmaf(av[i].z, bv[j].z, acc[i][j]);
          acc[i][j] = fmaf(av[i].w, bv[j].w, acc[i][j]);
        }
    }
#pragma unroll
    for (int i = 0; i < 4; ++i)
#pragma unroll
      for (int j = 0; j < 8; ++j) {
        float v = acc[i][j];
        lmax = fmaxf(lmax, v);
        lsum += v;
        lsumsq = fmaf(v, v, lsumsq);
        int bin = (int)((v + 1.f) * 8.f);
        bin = bin < 0 ? 0 : (bin > BINS - 1 ? BINS - 1 : bin);
        atomicAdd(&shist[rep + bin], 1);
      }
  }
#pragma unroll
  for (int d = 1; d < 64; d <<= 1) {
    lsum += __shfl_xor(lsum, d, 64);
    lsumsq += __shfl_xor(lsumsq, d, 64);
    lmax = fmaxf(lmax, __shfl_xor(lmax, d, 64));
  }
  int wv = tid >> 6, lane = tid & 63;
  if (lane == 0) {
    sfin[wv][0] = lsum;
    sfin[wv][1] = lsumsq;
    sfin[wv][2] = lmax;
  }
  __syncthreads();
  if (tid == 0) {
    psum[blockIdx.x] = sfin[0][0] + sfin[1][0] + sfin[2][0] + sfin[3][0];
    psumsq[blockIdx.x] = sfin[0][1] + sfin[1][1] + sfin[2][1] + sfin[3][1];
    pmax[blockIdx.x] = fmaxf(fmaxf(sfin[0][2], sfin[1][2]), fmaxf(sfin[2][2], sfin[3][2]));
  }
  if (tid < BINS) {
    int tot = 0;
    for (int r = 0; r < 64; ++r) tot += shist[r * 17 + tid];
    phist[blockIdx.x * BINS + tid] = tot;
  }
}

// ---------------- final feature assembly + MLP ----------------
__global__ __launch_bounds__(64) void k_final(const float* __restrict__ pg1, const float* __restrict__ pg2,
                                              const float* __restrict__ psum, const float* __restrict__ psumsq,
                                              const float* __restrict__ pmax, const int* __restrict__ phist,
                                              const float* __restrict__ w1, const float* __restrict__ b1,
                                              const float* __restrict__ w2, const float* __restrict__ b2,
                                              const float* __restrict__ w3, const float* __restrict__ b3,
                                              float* __restrict__ out) {
  __shared__ float f[FIN + 1];
  __shared__ float t1[64];
  __shared__ float t2[32];
  int g = blockIdx.x, t = threadIdx.x;
  {
    float s1v = 0.f, s2v = 0.f;
#pragma unroll
    for (int r = 0; r < 16; ++r) {
      s1v += pg1[(g * 16 + r) * 64 + t];
      s2v += pg2[(g * 16 + r) * 64 + t];
    }
    f[t]      = s1v * (1.f / NPG);
    f[64 + t] = s2v * (1.f / NPG);
  }
  if (t < BINS) {
    int tot = 0;
#pragma unroll
    for (int r = 0; r < 8; ++r) tot += phist[(g * 8 + r) * BINS + t];
    f[2 * H + t] = (float)tot * (1.f / 262144.f);
  }
  if (t == 0) {
    float s = 0.f, ss = 0.f, mx = -2.f;
#pragma unroll
    for (int r = 0; r < 8; ++r) {
      s += psum[g * 8 + r];
      ss += psumsq[g * 8 + r];
      mx = fmaxf(mx, pmax[g * 8 + r]);
    }
    const float inv = 1.f / 262144.f;
    float mean = s * inv;
    float var = fmaxf(ss * inv - mean * mean, 0.f);
    f[144] = mean;
    f[145] = mx;
    f[146] = sqrtf(var);
  }
  __syncthreads();
  float acc = b1[t];
  for (int k = 0; k < FIN; ++k) acc = fmaf(f[k], w1[k * 64 + t], acc);
  t1[t] = fmaxf(acc, 0.f);
  __syncthreads();
  if (t < 32) {
    float a2 = b2[t];
#pragma unroll 8
    for (int k = 0; k < 64; ++k) a2 = fmaf(t1[k], w2[k * 32 + t], a2);
    t2[t] = fmaxf(a2, 0.f);
  }
  __syncthreads();
  if (t == 0) {
    float a3 = b3[0];
#pragma unroll
    for (int k = 0; k < 32; ++k) a3 = fmaf(t2[k], w3[k], a3);
    out[g] = a3;
  }
}

}  // namespace

extern "C" void kernel_launch(void* const* d_in, const int* in_sizes, int n_in, void* d_out, int out_size,
                              void* d_ws, size_t ws_size, hipStream_t stream) {
  const float* x1 = (const float*)d_in[0];
  const int* e1 = (const int*)d_in[1];
  const float* x2 = (const float*)d_in[3];
  const int* e2 = (const int*)d_in[4];
  const float* enc_w1 = (const float*)d_in[6];
  const float* enc_b1 = (const float*)d_in[7];
  const float* enc_w2 = (const float*)d_in[8];
  const float* enc_b2 = (const float*)d_in[9];
  const float* enc_w3 = (const float*)d_in[10];
  const float* enc_b3 = (const float*)d_in[11];
  const float* enc_w4 = (const float*)d_in[12];
  const float* enc_b4 = (const float*)d_in[13];
  const float* mw1 = (const float*)d_in[14];
  const float* mb1 = (const float*)d_in[15];
  const float* mw2 = (const float*)d_in[16];
  const float* mb2 = (const float*)d_in[17];
  const float* mw3 = (const float*)d_in[18];
  const float* mb3 = (const float*)d_in[19];
  float* out = (float*)d_out;

  char* wsc = (char*)d_ws;
  size_t off = 0;
  auto alloc = [&](size_t bytes) -> void* {
    void* p = wsc + off;
    off += (bytes + 255) & ~(size_t)255;
    return p;
  };
  float* Hn = (float*)alloc((size_t)N2 * H * 4);          // 32 MB (normalized embeddings)
  __half* yH = (__half*)alloc((size_t)N2 * H * 2);        // 16 MB
  __half* zH = (__half*)alloc((size_t)N2 * H * 2);        // 16 MB (aliased as ebuf during CSR build)
  int* rowptr = (int*)alloc((size_t)(N2 + 1) * 4);
  int* colidx = (int*)alloc((size_t)2 * E * 4);           // 8 MB
  int* bcnt = (int*)alloc((size_t)NSLICE * NBUCKET * 4);  // 1 MB
  int* boffs = (int*)alloc((size_t)NBUCKET * NSLICE * 4); // 1 MB
  int* tot = (int*)alloc((size_t)NBUCKET * 4);
  float* pg = (float*)alloc((size_t)(N2 / 32) * 64 * 4);  // 1 MB
  float* psum = (float*)alloc(1024 * 4);
  float* psumsq = (float*)alloc(1024 * 4);
  float* pmaxa = (float*)alloc(1024 * 4);
  int* phist = (int*)alloc((size_t)1024 * BINS * 4);
  (void)ws_size;
  (void)in_sizes;
  (void)n_in;
  (void)out_size;

  const int* src1 = e1;
  const int* dst1 = e1 + E;
  const int* src2 = e2;
  const int* dst2 = e2 + E;
  int* ebuf = (int*)zH;  // 8 MB; consumed by k_p6 before k_gmid writes zH

  // CSR build (LDS-atomic bucket scheme) + xw co-scheduled; 0 global atomics
  k_p1_xw<<<NSLICE + N2 / 32, 256, 0, stream>>>(dst1, dst2, bcnt, x1, x2, enc_w1, yH);
  k_scanrows<<<NBUCKET, 256, 0, stream>>>(bcnt, boffs, tot);
  k_p5<<<NSLICE, 256, 0, stream>>>(src1, dst1, src2, dst2, boffs, tot, ebuf);
  k_p6<<<NBUCKET, 256, 0, stream>>>(ebuf, tot, rowptr, colidx);

  // encoder over 2N nodes, gather+dense fused per layer
  k_gmid<<<N2 / 32, 256, 0, stream>>>(yH, rowptr, colidx, enc_b1, enc_w2, enc_b2, enc_w3, zH);
  k_glast<<<N2 / 32, 256, 0, stream>>>(zH, rowptr, colidx, enc_b3, enc_w4, enc_b4, Hn, pg);

  k_sim<<<B * 8, 256, 0, stream>>>(Hn, psum, psumsq, pmaxa, phist);
  k_final<<<B, 64, 0, stream>>>(pg, pg + (size_t)2048 * 64, psum, psumsq, pmaxa, phist, mw1, mb1, mw2, mb2,
                                mw3, mb3, out);
}

// Round 7
// 420.125 us; speedup vs baseline: 1.1067x; 1.1067x over previous
//
#include <hip/hip_runtime.h>
#include <hip/hip_bf16.h>
#include <hip/hip_fp16.h>

namespace {

constexpr int N    = 65536;
constexpr int E    = 1048576;
constexpr int N2   = 2 * N;      // both sides concatenated
constexpr int B    = 128;
constexpr int NPG  = 512;
constexpr int IN   = 128;
constexpr int H    = 64;
constexpr int BINS = 16;
constexpr int FIN  = 2 * H + BINS + 3;  // 147
// CSR bucket scheme: 512 buckets of 256 dsts; 512 slices of 4096 edges.
constexpr int NBUCKET = 512;
constexpr int NSLICE  = 512;
constexpr int SLICE_E = 4096;

// ---------------- P1 (blocks 0..511): bucket histogram per slice, LDS only.
// ---------------- blocks 512..4607: y = x @ W1 -> fp16 (independent work, co-scheduled).

__global__ __launch_bounds__(256) void k_p1_xw(const int* __restrict__ dst1, const int* __restrict__ dst2,
                                               int* __restrict__ bcnt,
                                               const float* __restrict__ x1, const float* __restrict__ x2,
                                               const float* __restrict__ W, __half* __restrict__ y) {
  __shared__ float sW[IN * H];                     // 32 KB
  __shared__ __align__(16) float sx[4][IN][8];     // 16 KB
  __shared__ int hist[NBUCKET];                    // 2 KB
  int b = blockIdx.x, tid = threadIdx.x;
  if (b < NSLICE) {
    hist[tid] = 0;
    hist[tid + 256] = 0;
    __syncthreads();
    const int* d = (b < 256) ? dst1 : dst2;
    int ebase = (b & 255) * SLICE_E;
    int boff = (b < 256) ? 0 : 256;  // side2 dst+N -> bucket+256 (N = 256*256)
    for (int i = tid; i < SLICE_E; i += 256) atomicAdd(&hist[boff + (d[ebase + i] >> 8)], 1);
    __syncthreads();
    for (int k = tid; k < NBUCKET; k += 256) bcnt[b * NBUCKET + k] = hist[k];
  } else {
    int bx = b - NSLICE;
    int lane = tid & 63, sub = tid >> 6;
    for (int i = tid; i < IN * H; i += 256) sW[i] = W[i];
    __syncthreads();
    int nbase = bx * 32 + sub * 8;
    const float* xp = (nbase < N) ? (x1 + (size_t)nbase * IN) : (x2 + (size_t)(nbase - N) * IN);
#pragma unroll
    for (int nd = 0; nd < 8; ++nd) {
      const float* xr = xp + (size_t)nd * IN;
      sx[sub][lane][nd]      = xr[lane];
      sx[sub][lane + 64][nd] = xr[lane + 64];
    }
    // same-wave LDS producer/consumer: no barrier needed
    float acc[8];
#pragma unroll
    for (int nd = 0; nd < 8; ++nd) acc[nd] = 0.f;
    for (int k = 0; k < IN; ++k) {
      float wv = sW[k * H + lane];
      const float* p = &sx[sub][k][0];
      float4 lo = *(const float4*)(p);
      float4 hi = *(const float4*)(p + 4);
      acc[0] = fmaf(lo.x, wv, acc[0]); acc[1] = fmaf(lo.y, wv, acc[1]);
      acc[2] = fmaf(lo.z, wv, acc[2]); acc[3] = fmaf(lo.w, wv, acc[3]);
      acc[4] = fmaf(hi.x, wv, acc[4]); acc[5] = fmaf(hi.y, wv, acc[5]);
      acc[6] = fmaf(hi.z, wv, acc[6]); acc[7] = fmaf(hi.w, wv, acc[7]);
    }
#pragma unroll
    for (int nd = 0; nd < 8; ++nd) y[(size_t)(nbase + nd) * H + lane] = __float2half(acc[nd]);
  }
}

// P2: per-bucket exclusive scan across slices. boffs[bucket][slice]; tot[bucket].
__global__ __launch_bounds__(256) void k_scanrows(const int* __restrict__ bcnt, int* __restrict__ boffs,
                                                  int* __restrict__ tot) {
  __shared__ int s[NSLICE];
  int b = blockIdx.x, t = threadIdx.x;
  int v0 = bcnt[t * NBUCKET + b], v1 = bcnt[(t + 256) * NBUCKET + b];
  s[t] = v0;
  s[t + 256] = v1;
  __syncthreads();
  for (int d = 1; d < NSLICE; d <<= 1) {
    int a0 = (t >= d) ? s[t - d] : 0;
    int a1 = (t + 256 >= d) ? s[t + 256 - d] : 0;
    __syncthreads();
    s[t] += a0;
    s[t + 256] += a1;
    __syncthreads();
  }
  boffs[b * NSLICE + t] = s[t] - v0;
  boffs[b * NSLICE + t + 256] = s[t + 256] - v1;
  if (t == 255) tot[b] = s[NSLICE - 1];
}

// P5: scatter edges into bucket-grouped ebuf, packed (dstLow8 << 17) | src.
// LDS cursors only; bucket base scan recomputed in LDS (no extra launch).
__global__ __launch_bounds__(256) void k_p5(const int* __restrict__ src1, const int* __restrict__ dst1,
                                            const int* __restrict__ src2, const int* __restrict__ dst2,
                                            const int* __restrict__ boffs, const int* __restrict__ tot,
                                            int* __restrict__ ebuf) {
  __shared__ int stot[NBUCKET];
  __shared__ int sofs[NBUCKET];
  __shared__ int cur[NBUCKET];
  int b = blockIdx.x, tid = threadIdx.x;
  int v0 = tot[tid], v1 = tot[tid + 256];
  stot[tid] = v0;
  stot[tid + 256] = v1;
  __syncthreads();
  for (int d = 1; d < NBUCKET; d <<= 1) {
    int a0 = (tid >= d) ? stot[tid - d] : 0;
    int a1 = (tid + 256 >= d) ? stot[tid + 256 - d] : 0;
    __syncthreads();
    stot[tid] += a0;
    stot[tid + 256] += a1;
    __syncthreads();
  }
  sofs[tid]       = stot[tid] - v0 + boffs[tid * NSLICE + b];
  sofs[tid + 256] = stot[tid + 256] - v1 + boffs[(tid + 256) * NSLICE + b];
  cur[tid] = 0;
  cur[tid + 256] = 0;
  __syncthreads();
  const int* sr = (b < 256) ? src1 : src2;
  const int* d  = (b < 256) ? dst1 : dst2;
  int ebase = (b & 255) * SLICE_E;
  int off = (b < 256) ? 0 : N;
  int boff2 = (b < 256) ? 0 : 256;
  for (int i = tid; i < SLICE_E; i += 256) {
    int dd = d[ebase + i];
    int sv = off + sr[ebase + i];
    int bucket = boff2 + (dd >> 8);
    int r = atomicAdd(&cur[bucket], 1);
    ebuf[sofs[bucket] + r] = ((dd & 255) << 17) | sv;
  }
}

// P6: per-bucket CSR finalize (contiguous edge segment). LDS count+scan+scatter.
__global__ __launch_bounds__(256) void k_p6(const int* __restrict__ ebuf, const int* __restrict__ tot,
                                            int* __restrict__ rowptr, int* __restrict__ col) {
  __shared__ int stot[NBUCKET];
  __shared__ int c256[256];
  __shared__ int lofs[256];
  int b = blockIdx.x, t = threadIdx.x;
  {
    int v0 = tot[t], v1 = tot[t + 256];
    stot[t] = v0;
    stot[t + 256] = v1;
    __syncthreads();
    for (int d = 1; d < NBUCKET; d <<= 1) {
      int a0 = (t >= d) ? stot[t - d] : 0;
      int a1 = (t + 256 >= d) ? stot[t + 256 - d] : 0;
      __syncthreads();
      stot[t] += a0;
      stot[t + 256] += a1;
      __syncthreads();
    }
  }
  int e0 = (b == 0) ? 0 : stot[b - 1];
  int e1 = stot[b];
  c256[t] = 0;
  __syncthreads();
  for (int i = e0 + t; i < e1; i += 256) atomicAdd(&c256[(ebuf[i] >> 17) & 255], 1);
  __syncthreads();
  int v = c256[t];
  lofs[t] = v;
  __syncthreads();
  for (int d = 1; d < 256; d <<= 1) {
    int a = (t >= d) ? lofs[t - d] : 0;
    __syncthreads();
    lofs[t] += a;
    __syncthreads();
  }
  int excl = lofs[t] - v;
  rowptr[b * 256 + t] = e0 + excl;
  if (b == 0 && t == 0) rowptr[N2] = 2 * E;
  c256[t] = 0;
  lofs[t] = excl;
  __syncthreads();
  for (int i = e0 + t; i < e1; i += 256) {
    int pk = ebuf[i];
    int dl = (pk >> 17) & 255;
    int r = atomicAdd(&c256[dl], 1);
    col[e0 + lofs[dl] + r] = pk & 0x1FFFF;
  }
}

// ---------------- gather: out[n] = relu(in[n] + sum_{j->n} in[j] + bias), fp16 rows ----------------
// One wave per node; 16 independent 128B row loads in flight per batch.

__global__ __launch_bounds__(256) void k_gather(const __half* __restrict__ in, const int* __restrict__ rowptr,
                                                const int* __restrict__ col, const float* __restrict__ bias,
                                                __half* __restrict__ outb) {
  int tid = threadIdx.x, lane = tid & 63, sub = tid >> 6;
  int n = blockIdx.x * 4 + sub;
  int p0 = rowptr[n], p1 = rowptr[n + 1];
  float a = __half2float(in[(size_t)n * H + lane]) + bias[lane];
  int p = p0;
  for (; p + 16 <= p1; p += 16) {
    int myc = (lane < 16) ? col[p + lane] : 0;
    float v[16];
#pragma unroll
    for (int i = 0; i < 16; ++i) {
      int c = __shfl(myc, i, 64);
      v[i] = __half2float(in[(size_t)c * H + lane]);
    }
#pragma unroll
    for (int i = 0; i < 16; ++i) a += v[i];
  }
  if (p < p1) {
    int cnt = p1 - p;
    int myc = (lane < 16 && p + lane < p1) ? col[p + lane] : 0;
#pragma unroll
    for (int i = 0; i < 16; ++i) {
      if (i < cnt) {
        int c = __shfl(myc, i, 64);
        a += __half2float(in[(size_t)c * H + lane]);
      }
    }
  }
  outb[(size_t)n * H + lane] = __float2half(fmaxf(a, 0.f));
}

// ---------------- dense helpers ----------------

__device__ __forceinline__ void fma8(float (&acc)[8], const float* p, float wv) {
  float4 lo = *(const float4*)(p);
  float4 hi = *(const float4*)(p + 4);
  acc[0] = fmaf(lo.x, wv, acc[0]);
  acc[1] = fmaf(lo.y, wv, acc[1]);
  acc[2] = fmaf(lo.z, wv, acc[2]);
  acc[3] = fmaf(lo.w, wv, acc[3]);
  acc[4] = fmaf(hi.x, wv, acc[4]);
  acc[5] = fmaf(hi.y, wv, acc[5]);
  acc[6] = fmaf(hi.z, wv, acc[6]);
  acc[7] = fmaf(hi.w, wv, acc[7]);
}

// out = relu(in@Wa + ba) @ Wb    (fp16 in/out, f32 math)
__global__ __launch_bounds__(256) void k_mid(const __half* __restrict__ in, const float* __restrict__ Wa,
                                             const float* __restrict__ ba, const float* __restrict__ Wb,
                                             __half* __restrict__ outb) {
  __shared__ float sWa[H * H];
  __shared__ float sWb[H * H];
  __shared__ __align__(16) float st[4][H][8];
  int tid = threadIdx.x, lane = tid & 63, sub = tid >> 6;
  for (int i = tid; i < H * H; i += 256) sWa[i] = Wa[i];
  for (int i = tid; i < H * H; i += 256) sWb[i] = Wb[i];
  float biasA = ba[lane];
  __syncthreads();
  int nbase = blockIdx.x * 32 + sub * 8;
#pragma unroll
  for (int nd = 0; nd < 8; ++nd) st[sub][lane][nd] = __half2float(in[(size_t)(nbase + nd) * H + lane]);
  float acc[8];
#pragma unroll
  for (int nd = 0; nd < 8; ++nd) acc[nd] = biasA;
  for (int k = 0; k < H; ++k) fma8(acc, &st[sub][k][0], sWa[k * H + lane]);
#pragma unroll
  for (int nd = 0; nd < 8; ++nd) st[sub][lane][nd] = fmaxf(acc[nd], 0.f);
  float acc2[8];
#pragma unroll
  for (int nd = 0; nd < 8; ++nd) acc2[nd] = 0.f;
  for (int k = 0; k < H; ++k) fma8(acc2, &st[sub][k][0], sWb[k * H + lane]);
#pragma unroll
  for (int nd = 0; nd < 8; ++nd) outb[(size_t)(nbase + nd) * H + lane] = __float2half(acc2[nd]);
}

// h = relu(in@Wa + ba); write L2-normalized h (f32) + per-32-node-tile pool partials.
__global__ __launch_bounds__(256) void k_last(const __half* __restrict__ in, const float* __restrict__ Wa,
                                              const float* __restrict__ ba, float* __restrict__ outn,
                                              float* __restrict__ pg) {
  __shared__ float sWa[H * H];
  __shared__ __align__(16) float st[4][H][8];
  __shared__ float sacc[4][64];
  int tid = threadIdx.x, lane = tid & 63, sub = tid >> 6;
  for (int i = tid; i < H * H; i += 256) sWa[i] = Wa[i];
  float biasA = ba[lane];
  __syncthreads();
  int nbase = blockIdx.x * 32 + sub * 8;
#pragma unroll
  for (int nd = 0; nd < 8; ++nd) st[sub][lane][nd] = __half2float(in[(size_t)(nbase + nd) * H + lane]);
  float acc[8];
#pragma unroll
  for (int nd = 0; nd < 8; ++nd) acc[nd] = biasA;
  for (int k = 0; k < H; ++k) fma8(acc, &st[sub][k][0], sWa[k * H + lane]);
  float psum = 0.f;
#pragma unroll
  for (int nd = 0; nd < 8; ++nd) {
    float h = fmaxf(acc[nd], 0.f);
    psum += h;
    float ss = h * h;
#pragma unroll
    for (int d = 1; d < 64; d <<= 1) ss += __shfl_xor(ss, d, 64);
    outn[(size_t)(nbase + nd) * H + lane] = h / fmaxf(sqrtf(ss), 1e-12f);
  }
  sacc[sub][lane] = psum;
  __syncthreads();
  if (sub == 0) pg[blockIdx.x * 64 + lane] = sacc[0][lane] + sacc[1][lane] + sacc[2][lane] + sacc[3][lane];
}

// ---------------- fused sim + hist + stats (float4 LDS, XOR swizzle) ----------------
__global__ __launch_bounds__(256, 3) void k_sim(const float* __restrict__ Hn, float* __restrict__ psum,
                                                float* __restrict__ psumsq, float* __restrict__ pmax,
                                                int* __restrict__ phist) {
  __shared__ float4 s1[64 * 16];   // 16 KB
  __shared__ float4 s2[128 * 16];  // 32 KB
  __shared__ int shist[64 * 17];   // 4.25 KB, 64 replicas stride 17
  __shared__ float sfin[4][4];
  int tid = threadIdx.x;
  int g = blockIdx.x >> 3, rt = blockIdx.x & 7;
  for (int i = tid; i < 64 * 17; i += 256) shist[i] = 0;
  const float4* b1p = (const float4*)(Hn + ((size_t)g * NPG + rt * 64) * H);
  for (int i = tid; i < 1024; i += 256) {
    int row = i >> 4, k4 = i & 15;
    s1[(row << 4) | (k4 ^ (row & 15))] = b1p[i];
  }
  int ty = tid >> 4, tx = tid & 15;
  int rep = (tid & 63) * 17;
  float lmax = -2.f, lsum = 0.f, lsumsq = 0.f;
  const float* H2 = Hn + (size_t)N * H;
  for (int ch = 0; ch < 4; ++ch) {
    __syncthreads();
    const float4* b2p = (const float4*)(H2 + ((size_t)g * NPG + ch * 128) * H);
    for (int i = tid; i < 2048; i += 256) {
      int row = i >> 4, k4 = i & 15;
      s2[(row << 4) | (k4 ^ (row & 15))] = b2p[i];
    }
    __syncthreads();
    float acc[4][8];
#pragma unroll
    for (int i = 0; i < 4; ++i)
#pragma unroll
      for (int j = 0; j < 8; ++j) acc[i][j] = 0.f;
#pragma unroll 2
    for (int k4 = 0; k4 < 16; ++k4) {
      int ka = k4 ^ ty, kb = k4 ^ tx;
      float4 av[4], bv[8];
#pragma unroll
      for (int i = 0; i < 4; ++i) av[i] = s1[((ty + 16 * i) << 4) | ka];
#pragma unroll
      for (int j = 0; j < 8; ++j) bv[j] = s2[((tx + 16 * j) << 4) | kb];
#pragma unroll
      for (int i = 0; i < 4; ++i)
#pragma unroll
        for (int j = 0; j < 8; ++j) {
          acc[i][j] = fmaf(av[i].x, bv[j].x, acc[i][j]);
          acc[i][j] = fmaf(av[i].y, bv[j].y, acc[i][j]);
          acc[i][j] = fmaf(av[i].z, bv[j].z, acc[i][j]);
          acc[i][j] = fmaf(av[i].w, bv[j].w, acc[i][j]);
        }
    }
#pragma unroll
    for (int i = 0; i < 4; ++i)
#pragma unroll
      for (int j = 0; j < 8; ++j) {
        float v = acc[i][j];
        lmax = fmaxf(lmax, v);
        lsum += v;
        lsumsq = fmaf(v, v, lsumsq);
        int bin = (int)((v + 1.f) * 8.f);
        bin = bin < 0 ? 0 : (bin > BINS - 1 ? BINS - 1 : bin);
        atomicAdd(&shist[rep + bin], 1);
      }
  }
#pragma unroll
  for (int d = 1; d < 64; d <<= 1) {
    lsum += __shfl_xor(lsum, d, 64);
    lsumsq += __shfl_xor(lsumsq, d, 64);
    lmax = fmaxf(lmax, __shfl_xor(lmax, d, 64));
  }
  int wv = tid >> 6, lane = tid & 63;
  if (lane == 0) {
    sfin[wv][0] = lsum;
    sfin[wv][1] = lsumsq;
    sfin[wv][2] = lmax;
  }
  __syncthreads();
  if (tid == 0) {
    psum[blockIdx.x] = sfin[0][0] + sfin[1][0] + sfin[2][0] + sfin[3][0];
    psumsq[blockIdx.x] = sfin[0][1] + sfin[1][1] + sfin[2][1] + sfin[3][1];
    pmax[blockIdx.x] = fmaxf(fmaxf(sfin[0][2], sfin[1][2]), fmaxf(sfin[2][2], sfin[3][2]));
  }
  if (tid < BINS) {
    int tot = 0;
    for (int r = 0; r < 64; ++r) tot += shist[r * 17 + tid];
    phist[blockIdx.x * BINS + tid] = tot;
  }
}

// ---------------- final feature assembly + MLP ----------------
__global__ __launch_bounds__(64) void k_final(const float* __restrict__ pg1, const float* __restrict__ pg2,
                                              const float* __restrict__ psum, const float* __restrict__ psumsq,
                                              const float* __restrict__ pmax, const int* __restrict__ phist,
                                              const float* __restrict__ w1, const float* __restrict__ b1,
                                              const float* __restrict__ w2, const float* __restrict__ b2,
                                              const float* __restrict__ w3, const float* __restrict__ b3,
                                              float* __restrict__ out) {
  __shared__ float f[FIN + 1];
  __shared__ float t1[64];
  __shared__ float t2[32];
  int g = blockIdx.x, t = threadIdx.x;
  {
    float s1v = 0.f, s2v = 0.f;
#pragma unroll
    for (int r = 0; r < 16; ++r) {
      s1v += pg1[(g * 16 + r) * 64 + t];
      s2v += pg2[(g * 16 + r) * 64 + t];
    }
    f[t]      = s1v * (1.f / NPG);
    f[64 + t] = s2v * (1.f / NPG);
  }
  if (t < BINS) {
    int tot = 0;
#pragma unroll
    for (int r = 0; r < 8; ++r) tot += phist[(g * 8 + r) * BINS + t];
    f[2 * H + t] = (float)tot * (1.f / 262144.f);
  }
  if (t == 0) {
    float s = 0.f, ss = 0.f, mx = -2.f;
#pragma unroll
    for (int r = 0; r < 8; ++r) {
      s += psum[g * 8 + r];
      ss += psumsq[g * 8 + r];
      mx = fmaxf(mx, pmax[g * 8 + r]);
    }
    const float inv = 1.f / 262144.f;
    float mean = s * inv;
    float var = fmaxf(ss * inv - mean * mean, 0.f);
    f[144] = mean;
    f[145] = mx;
    f[146] = sqrtf(var);
  }
  __syncthreads();
  float acc = b1[t];
  for (int k = 0; k < FIN; ++k) acc = fmaf(f[k], w1[k * 64 + t], acc);
  t1[t] = fmaxf(acc, 0.f);
  __syncthreads();
  if (t < 32) {
    float a2 = b2[t];
#pragma unroll 8
    for (int k = 0; k < 64; ++k) a2 = fmaf(t1[k], w2[k * 32 + t], a2);
    t2[t] = fmaxf(a2, 0.f);
  }
  __syncthreads();
  if (t == 0) {
    float a3 = b3[0];
#pragma unroll
    for (int k = 0; k < 32; ++k) a3 = fmaf(t2[k], w3[k], a3);
    out[g] = a3;
  }
}

}  // namespace

extern "C" void kernel_launch(void* const* d_in, const int* in_sizes, int n_in, void* d_out, int out_size,
                              void* d_ws, size_t ws_size, hipStream_t stream) {
  const float* x1 = (const float*)d_in[0];
  const int* e1 = (const int*)d_in[1];
  const float* x2 = (const float*)d_in[3];
  const int* e2 = (const int*)d_in[4];
  const float* enc_w1 = (const float*)d_in[6];
  const float* enc_b1 = (const float*)d_in[7];
  const float* enc_w2 = (const float*)d_in[8];
  const float* enc_b2 = (const float*)d_in[9];
  const float* enc_w3 = (const float*)d_in[10];
  const float* enc_b3 = (const float*)d_in[11];
  const float* enc_w4 = (const float*)d_in[12];
  const float* enc_b4 = (const float*)d_in[13];
  const float* mw1 = (const float*)d_in[14];
  const float* mb1 = (const float*)d_in[15];
  const float* mw2 = (const float*)d_in[16];
  const float* mb2 = (const float*)d_in[17];
  const float* mw3 = (const float*)d_in[18];
  const float* mb3 = (const float*)d_in[19];
  float* out = (float*)d_out;

  char* wsc = (char*)d_ws;
  size_t off = 0;
  auto alloc = [&](size_t bytes) -> void* {
    void* p = wsc + off;
    off += (bytes + 255) & ~(size_t)255;
    return p;
  };
  float* Hn = (float*)alloc((size_t)N2 * H * 4);          // 32 MB (normalized embeddings)
  __half* yH = (__half*)alloc((size_t)N2 * H * 2);        // 16 MB
  __half* tH = (__half*)alloc((size_t)N2 * H * 2);        // 16 MB (aliased as ebuf during CSR build)
  __half* zH = (__half*)alloc((size_t)N2 * H * 2);        // 16 MB
  __half* t2H = (__half*)alloc((size_t)N2 * H * 2);       // 16 MB
  int* rowptr = (int*)alloc((size_t)(N2 + 1) * 4);
  int* colidx = (int*)alloc((size_t)2 * E * 4);           // 8 MB
  int* bcnt = (int*)alloc((size_t)NSLICE * NBUCKET * 4);  // 1 MB
  int* boffs = (int*)alloc((size_t)NBUCKET * NSLICE * 4); // 1 MB
  int* tot = (int*)alloc((size_t)NBUCKET * 4);
  float* pg = (float*)alloc((size_t)(N2 / 32) * 64 * 4);  // 1 MB
  float* psum = (float*)alloc(1024 * 4);
  float* psumsq = (float*)alloc(1024 * 4);
  float* pmaxa = (float*)alloc(1024 * 4);
  int* phist = (int*)alloc((size_t)1024 * BINS * 4);
  (void)ws_size;
  (void)in_sizes;
  (void)n_in;
  (void)out_size;

  const int* src1 = e1;
  const int* dst1 = e1 + E;
  const int* src2 = e2;
  const int* dst2 = e2 + E;
  int* ebuf = (int*)tH;  // 8 MB; consumed by k_p6 before k_gather writes tH

  // CSR build (LDS-atomic bucket scheme) + xw co-scheduled; 0 global atomics
  k_p1_xw<<<NSLICE + N2 / 32, 256, 0, stream>>>(dst1, dst2, bcnt, x1, x2, enc_w1, yH);
  k_scanrows<<<NBUCKET, 256, 0, stream>>>(bcnt, boffs, tot);
  k_p5<<<NSLICE, 256, 0, stream>>>(src1, dst1, src2, dst2, boffs, tot, ebuf);
  k_p6<<<NBUCKET, 256, 0, stream>>>(ebuf, tot, rowptr, colidx);

  // encoder over 2N nodes (split kernels: gather = 1 wave/node for latency hiding)
  k_gather<<<N2 / 4, 256, 0, stream>>>(yH, rowptr, colidx, enc_b1, tH);
  k_mid<<<N2 / 32, 256, 0, stream>>>(tH, enc_w2, enc_b2, enc_w3, zH);
  k_gather<<<N2 / 4, 256, 0, stream>>>(zH, rowptr, colidx, enc_b3, t2H);
  k_last<<<N2 / 32, 256, 0, stream>>>(t2H, enc_w4, enc_b4, Hn, pg);

  k_sim<<<B * 8, 256, 0, stream>>>(Hn, psum, psumsq, pmaxa, phist);
  k_final<<<B, 64, 0, stream>>>(pg, pg + (size_t)2048 * 64, psum, psumsq, pmaxa, phist, mw1, mb1, mw2, mb2,
                                mw3, mb3, out);
}

// Round 8
// 371.805 us; speedup vs baseline: 1.2505x; 1.1300x over previous
//
#include <hip/hip_runtime.h>
#include <hip/hip_bf16.h>
#include <hip/hip_fp16.h>

namespace {

constexpr int N    = 65536;
constexpr int E    = 1048576;
constexpr int N2   = 2 * N;      // both sides concatenated
constexpr int B    = 128;
constexpr int NPG  = 512;
constexpr int IN   = 128;
constexpr int H    = 64;
constexpr int BINS = 16;
constexpr int FIN  = 2 * H + BINS + 3;  // 147
// CSR bucket scheme: 512 buckets of 256 dsts; 512 slices of 4096 edges.
constexpr int NBUCKET = 512;
constexpr int NSLICE  = 512;
constexpr int SLICE_E = 4096;

// ---------------- P1 (blocks 0..511): bucket histogram per slice, LDS only.
// ---------------- blocks 512..4607: y = x @ W1 -> fp16 (independent work, co-scheduled).

__global__ __launch_bounds__(256) void k_p1_xw(const int* __restrict__ dst1, const int* __restrict__ dst2,
                                               int* __restrict__ bcnt,
                                               const float* __restrict__ x1, const float* __restrict__ x2,
                                               const float* __restrict__ W, __half* __restrict__ y) {
  __shared__ float sW[IN * H];                     // 32 KB
  __shared__ __align__(16) float sx[4][IN][8];     // 16 KB
  __shared__ int hist[NBUCKET];                    // 2 KB
  int b = blockIdx.x, tid = threadIdx.x;
  if (b < NSLICE) {
    hist[tid] = 0;
    hist[tid + 256] = 0;
    __syncthreads();
    const int* d = (b < 256) ? dst1 : dst2;
    int ebase = (b & 255) * SLICE_E;
    int boff = (b < 256) ? 0 : 256;  // side2 dst+N -> bucket+256 (N = 256*256)
    for (int i = tid; i < SLICE_E; i += 256) atomicAdd(&hist[boff + (d[ebase + i] >> 8)], 1);
    __syncthreads();
    for (int k = tid; k < NBUCKET; k += 256) bcnt[b * NBUCKET + k] = hist[k];
  } else {
    int bx = b - NSLICE;
    int lane = tid & 63, sub = tid >> 6;
    for (int i = tid; i < IN * H; i += 256) sW[i] = W[i];
    __syncthreads();
    int nbase = bx * 32 + sub * 8;
    const float* xp = (nbase < N) ? (x1 + (size_t)nbase * IN) : (x2 + (size_t)(nbase - N) * IN);
#pragma unroll
    for (int nd = 0; nd < 8; ++nd) {
      const float* xr = xp + (size_t)nd * IN;
      sx[sub][lane][nd]      = xr[lane];
      sx[sub][lane + 64][nd] = xr[lane + 64];
    }
    // same-wave LDS producer/consumer: no barrier needed
    float acc[8];
#pragma unroll
    for (int nd = 0; nd < 8; ++nd) acc[nd] = 0.f;
    for (int k = 0; k < IN; ++k) {
      float wv = sW[k * H + lane];
      const float* p = &sx[sub][k][0];
      float4 lo = *(const float4*)(p);
      float4 hi = *(const float4*)(p + 4);
      acc[0] = fmaf(lo.x, wv, acc[0]); acc[1] = fmaf(lo.y, wv, acc[1]);
      acc[2] = fmaf(lo.z, wv, acc[2]); acc[3] = fmaf(lo.w, wv, acc[3]);
      acc[4] = fmaf(hi.x, wv, acc[4]); acc[5] = fmaf(hi.y, wv, acc[5]);
      acc[6] = fmaf(hi.z, wv, acc[6]); acc[7] = fmaf(hi.w, wv, acc[7]);
    }
#pragma unroll
    for (int nd = 0; nd < 8; ++nd) y[(size_t)(nbase + nd) * H + lane] = __float2half(acc[nd]);
  }
}

// P2: per-bucket exclusive scan across slices. boffs[bucket][slice]; tot[bucket].
__global__ __launch_bounds__(256) void k_scanrows(const int* __restrict__ bcnt, int* __restrict__ boffs,
                                                  int* __restrict__ tot) {
  __shared__ int s[NSLICE];
  int b = blockIdx.x, t = threadIdx.x;
  int v0 = bcnt[t * NBUCKET + b], v1 = bcnt[(t + 256) * NBUCKET + b];
  s[t] = v0;
  s[t + 256] = v1;
  __syncthreads();
  for (int d = 1; d < NSLICE; d <<= 1) {
    int a0 = (t >= d) ? s[t - d] : 0;
    int a1 = (t + 256 >= d) ? s[t + 256 - d] : 0;
    __syncthreads();
    s[t] += a0;
    s[t + 256] += a1;
    __syncthreads();
  }
  boffs[b * NSLICE + t] = s[t] - v0;
  boffs[b * NSLICE + t + 256] = s[t + 256] - v1;
  if (t == 255) tot[b] = s[NSLICE - 1];
}

// P5: scatter edges into bucket-grouped ebuf, packed (dstLow8 << 17) | src.
// LDS cursors only; bucket base scan recomputed in LDS (no extra launch).
__global__ __launch_bounds__(256) void k_p5(const int* __restrict__ src1, const int* __restrict__ dst1,
                                            const int* __restrict__ src2, const int* __restrict__ dst2,
                                            const int* __restrict__ boffs, const int* __restrict__ tot,
                                            int* __restrict__ ebuf) {
  __shared__ int stot[NBUCKET];
  __shared__ int sofs[NBUCKET];
  __shared__ int cur[NBUCKET];
  int b = blockIdx.x, tid = threadIdx.x;
  int v0 = tot[tid], v1 = tot[tid + 256];
  stot[tid] = v0;
  stot[tid + 256] = v1;
  __syncthreads();
  for (int d = 1; d < NBUCKET; d <<= 1) {
    int a0 = (tid >= d) ? stot[tid - d] : 0;
    int a1 = (tid + 256 >= d) ? stot[tid + 256 - d] : 0;
    __syncthreads();
    stot[tid] += a0;
    stot[tid + 256] += a1;
    __syncthreads();
  }
  sofs[tid]       = stot[tid] - v0 + boffs[tid * NSLICE + b];
  sofs[tid + 256] = stot[tid + 256] - v1 + boffs[(tid + 256) * NSLICE + b];
  cur[tid] = 0;
  cur[tid + 256] = 0;
  __syncthreads();
  const int* sr = (b < 256) ? src1 : src2;
  const int* d  = (b < 256) ? dst1 : dst2;
  int ebase = (b & 255) * SLICE_E;
  int off = (b < 256) ? 0 : N;
  int boff2 = (b < 256) ? 0 : 256;
  for (int i = tid; i < SLICE_E; i += 256) {
    int dd = d[ebase + i];
    int sv = off + sr[ebase + i];
    int bucket = boff2 + (dd >> 8);
    int r = atomicAdd(&cur[bucket], 1);
    ebuf[sofs[bucket] + r] = ((dd & 255) << 17) | sv;
  }
}

// P6: per-bucket CSR finalize (contiguous edge segment). LDS count+scan+scatter.
__global__ __launch_bounds__(256) void k_p6(const int* __restrict__ ebuf, const int* __restrict__ tot,
                                            int* __restrict__ rowptr, int* __restrict__ col) {
  __shared__ int stot[NBUCKET];
  __shared__ int c256[256];
  __shared__ int lofs[256];
  int b = blockIdx.x, t = threadIdx.x;
  {
    int v0 = tot[t], v1 = tot[t + 256];
    stot[t] = v0;
    stot[t + 256] = v1;
    __syncthreads();
    for (int d = 1; d < NBUCKET; d <<= 1) {
      int a0 = (t >= d) ? stot[t - d] : 0;
      int a1 = (t + 256 >= d) ? stot[t + 256 - d] : 0;
      __syncthreads();
      stot[t] += a0;
      stot[t + 256] += a1;
      __syncthreads();
    }
  }
  int e0 = (b == 0) ? 0 : stot[b - 1];
  int e1 = stot[b];
  c256[t] = 0;
  __syncthreads();
  for (int i = e0 + t; i < e1; i += 256) atomicAdd(&c256[(ebuf[i] >> 17) & 255], 1);
  __syncthreads();
  int v = c256[t];
  lofs[t] = v;
  __syncthreads();
  for (int d = 1; d < 256; d <<= 1) {
    int a = (t >= d) ? lofs[t - d] : 0;
    __syncthreads();
    lofs[t] += a;
    __syncthreads();
  }
  int excl = lofs[t] - v;
  rowptr[b * 256 + t] = e0 + excl;
  if (b == 0 && t == 0) rowptr[N2] = 2 * E;
  c256[t] = 0;
  lofs[t] = excl;
  __syncthreads();
  for (int i = e0 + t; i < e1; i += 256) {
    int pk = ebuf[i];
    int dl = (pk >> 17) & 255;
    int r = atomicAdd(&c256[dl], 1);
    col[e0 + lofs[dl] + r] = pk & 0x1FFFF;
  }
}

// ---------------- gather: out[n] = relu(in[n] + sum_{j->n} in[j] + bias), fp16 rows ----------------
// TWO nodes per wave (32 lanes each, __half2 loads): 2 edges per instruction round,
// 32 independent row loads in flight per wave.

__global__ __launch_bounds__(256) void k_gather(const __half* __restrict__ in, const int* __restrict__ rowptr,
                                                const int* __restrict__ col, const float* __restrict__ bias,
                                                __half* __restrict__ outb) {
  int tid = threadIdx.x;
  int lane32 = tid & 31;
  int n = blockIdx.x * 8 + (tid >> 5);
  const __half2* in2 = (const __half2*)in;     // row = 32 half2
  __half2* out2 = (__half2*)outb;
  float2 bias2 = ((const float2*)bias)[lane32];
  int p0 = rowptr[n], p1 = rowptr[n + 1];
  __half2 self = in2[(size_t)n * 32 + lane32];
  float ax = __half2float(self.x) + bias2.x;
  float ay = __half2float(self.y) + bias2.y;
  int p = p0;
  for (; p + 16 <= p1; p += 16) {
    int myc = (lane32 < 16) ? col[p + lane32] : 0;
    __half2 v[16];
#pragma unroll
    for (int i = 0; i < 16; ++i) {
      int c = __shfl(myc, i, 32);
      v[i] = in2[(size_t)c * 32 + lane32];
    }
#pragma unroll
    for (int i = 0; i < 16; ++i) {
      ax += __half2float(v[i].x);
      ay += __half2float(v[i].y);
    }
  }
  if (p < p1) {
    int cnt = p1 - p;
    int myc = (lane32 < 16 && p + lane32 < p1) ? col[p + lane32] : 0;
#pragma unroll
    for (int i = 0; i < 16; ++i) {
      if (i < cnt) {
        int c = __shfl(myc, i, 32);
        __half2 v = in2[(size_t)c * 32 + lane32];
        ax += __half2float(v.x);
        ay += __half2float(v.y);
      }
    }
  }
  __half2 o;
  o.x = __float2half(fmaxf(ax, 0.f));
  o.y = __float2half(fmaxf(ay, 0.f));
  out2[(size_t)n * 32 + lane32] = o;
}

// ---------------- dense helpers ----------------

__device__ __forceinline__ void fma8(float (&acc)[8], const float* p, float wv) {
  float4 lo = *(const float4*)(p);
  float4 hi = *(const float4*)(p + 4);
  acc[0] = fmaf(lo.x, wv, acc[0]);
  acc[1] = fmaf(lo.y, wv, acc[1]);
  acc[2] = fmaf(lo.z, wv, acc[2]);
  acc[3] = fmaf(lo.w, wv, acc[3]);
  acc[4] = fmaf(hi.x, wv, acc[4]);
  acc[5] = fmaf(hi.y, wv, acc[5]);
  acc[6] = fmaf(hi.z, wv, acc[6]);
  acc[7] = fmaf(hi.w, wv, acc[7]);
}

// out = relu(in@Wa + ba) @ Wb    (fp16 in/out, f32 math)
__global__ __launch_bounds__(256) void k_mid(const __half* __restrict__ in, const float* __restrict__ Wa,
                                             const float* __restrict__ ba, const float* __restrict__ Wb,
                                             __half* __restrict__ outb) {
  __shared__ float sWa[H * H];
  __shared__ float sWb[H * H];
  __shared__ __align__(16) float st[4][H][8];
  int tid = threadIdx.x, lane = tid & 63, sub = tid >> 6;
  for (int i = tid; i < H * H; i += 256) sWa[i] = Wa[i];
  for (int i = tid; i < H * H; i += 256) sWb[i] = Wb[i];
  float biasA = ba[lane];
  __syncthreads();
  int nbase = blockIdx.x * 32 + sub * 8;
#pragma unroll
  for (int nd = 0; nd < 8; ++nd) st[sub][lane][nd] = __half2float(in[(size_t)(nbase + nd) * H + lane]);
  float acc[8];
#pragma unroll
  for (int nd = 0; nd < 8; ++nd) acc[nd] = biasA;
  for (int k = 0; k < H; ++k) fma8(acc, &st[sub][k][0], sWa[k * H + lane]);
#pragma unroll
  for (int nd = 0; nd < 8; ++nd) st[sub][lane][nd] = fmaxf(acc[nd], 0.f);
  float acc2[8];
#pragma unroll
  for (int nd = 0; nd < 8; ++nd) acc2[nd] = 0.f;
  for (int k = 0; k < H; ++k) fma8(acc2, &st[sub][k][0], sWb[k * H + lane]);
#pragma unroll
  for (int nd = 0; nd < 8; ++nd) outb[(size_t)(nbase + nd) * H + lane] = __float2half(acc2[nd]);
}

// h = relu(in@Wa + ba); write L2-normalized h (f32) + per-32-node-tile pool partials.
__global__ __launch_bounds__(256) void k_last(const __half* __restrict__ in, const float* __restrict__ Wa,
                                              const float* __restrict__ ba, float* __restrict__ outn,
                                              float* __restrict__ pg) {
  __shared__ float sWa[H * H];
  __shared__ __align__(16) float st[4][H][8];
  __shared__ float sacc[4][64];
  int tid = threadIdx.x, lane = tid & 63, sub = tid >> 6;
  for (int i = tid; i < H * H; i += 256) sWa[i] = Wa[i];
  float biasA = ba[lane];
  __syncthreads();
  int nbase = blockIdx.x * 32 + sub * 8;
#pragma unroll
  for (int nd = 0; nd < 8; ++nd) st[sub][lane][nd] = __half2float(in[(size_t)(nbase + nd) * H + lane]);
  float acc[8];
#pragma unroll
  for (int nd = 0; nd < 8; ++nd) acc[nd] = biasA;
  for (int k = 0; k < H; ++k) fma8(acc, &st[sub][k][0], sWa[k * H + lane]);
  float psum = 0.f;
#pragma unroll
  for (int nd = 0; nd < 8; ++nd) {
    float h = fmaxf(acc[nd], 0.f);
    psum += h;
    float ss = h * h;
#pragma unroll
    for (int d = 1; d < 64; d <<= 1) ss += __shfl_xor(ss, d, 64);
    outn[(size_t)(nbase + nd) * H + lane] = h / fmaxf(sqrtf(ss), 1e-12f);
  }
  sacc[sub][lane] = psum;
  __syncthreads();
  if (sub == 0) pg[blockIdx.x * 64 + lane] = sacc[0][lane] + sacc[1][lane] + sacc[2][lane] + sacc[3][lane];
}

// ---------------- fused sim + hist + stats (float4 LDS, XOR swizzle) ----------------
__global__ __launch_bounds__(256, 3) void k_sim(const float* __restrict__ Hn, float* __restrict__ psum,
                                                float* __restrict__ psumsq, float* __restrict__ pmax,
                                                int* __restrict__ phist) {
  __shared__ float4 s1[64 * 16];   // 16 KB
  __shared__ float4 s2[128 * 16];  // 32 KB
  __shared__ int shist[64 * 17];   // 4.25 KB, 64 replicas stride 17
  __shared__ float sfin[4][4];
  int tid = threadIdx.x;
  int g = blockIdx.x >> 3, rt = blockIdx.x & 7;
  for (int i = tid; i < 64 * 17; i += 256) shist[i] = 0;
  const float4* b1p = (const float4*)(Hn + ((size_t)g * NPG + rt * 64) * H);
  for (int i = tid; i < 1024; i += 256) {
    int row = i >> 4, k4 = i & 15;
    s1[(row << 4) | (k4 ^ (row & 15))] = b1p[i];
  }
  int ty = tid >> 4, tx = tid & 15;
  int rep = (tid & 63) * 17;
  float lmax = -2.f, lsum = 0.f, lsumsq = 0.f;
  const float* H2 = Hn + (size_t)N * H;
  for (int ch = 0; ch < 4; ++ch) {
    __syncthreads();
    const float4* b2p = (const float4*)(H2 + ((size_t)g * NPG + ch * 128) * H);
    for (int i = tid; i < 2048; i += 256) {
      int row = i >> 4, k4 = i & 15;
      s2[(row << 4) | (k4 ^ (row & 15))] = b2p[i];
    }
    __syncthreads();
    float acc[4][8];
#pragma unroll
    for (int i = 0; i < 4; ++i)
#pragma unroll
      for (int j = 0; j < 8; ++j) acc[i][j] = 0.f;
#pragma unroll 2
    for (int k4 = 0; k4 < 16; ++k4) {
      int ka = k4 ^ ty, kb = k4 ^ tx;
      float4 av[4], bv[8];
#pragma unroll
      for (int i = 0; i < 4; ++i) av[i] = s1[((ty + 16 * i) << 4) | ka];
#pragma unroll
      for (int j = 0; j < 8; ++j) bv[j] = s2[((tx + 16 * j) << 4) | kb];
#pragma unroll
      for (int i = 0; i < 4; ++i)
#pragma unroll
        for (int j = 0; j < 8; ++j) {
          acc[i][j] = fmaf(av[i].x, bv[j].x, acc[i][j]);
          acc[i][j] = fmaf(av[i].y, bv[j].y, acc[i][j]);
          acc[i][j] = fmaf(av[i].z, bv[j].z, acc[i][j]);
          acc[i][j] = fmaf(av[i].w, bv[j].w, acc[i][j]);
        }
    }
#pragma unroll
    for (int i = 0; i < 4; ++i)
#pragma unroll
      for (int j = 0; j < 8; ++j) {
        float v = acc[i][j];
        lmax = fmaxf(lmax, v);
        lsum += v;
        lsumsq = fmaf(v, v, lsumsq);
        int bin = (int)((v + 1.f) * 8.f);
        bin = bin < 0 ? 0 : (bin > BINS - 1 ? BINS - 1 : bin);
        atomicAdd(&shist[rep + bin], 1);
      }
  }
#pragma unroll
  for (int d = 1; d < 64; d <<= 1) {
    lsum += __shfl_xor(lsum, d, 64);
    lsumsq += __shfl_xor(lsumsq, d, 64);
    lmax = fmaxf(lmax, __shfl_xor(lmax, d, 64));
  }
  int wv = tid >> 6, lane = tid & 63;
  if (lane == 0) {
    sfin[wv][0] = lsum;
    sfin[wv][1] = lsumsq;
    sfin[wv][2] = lmax;
  }
  __syncthreads();
  if (tid == 0) {
    psum[blockIdx.x] = sfin[0][0] + sfin[1][0] + sfin[2][0] + sfin[3][0];
    psumsq[blockIdx.x] = sfin[0][1] + sfin[1][1] + sfin[2][1] + sfin[3][1];
    pmax[blockIdx.x] = fmaxf(fmaxf(sfin[0][2], sfin[1][2]), fmaxf(sfin[2][2], sfin[3][2]));
  }
  if (tid < BINS) {
    int tot = 0;
    for (int r = 0; r < 64; ++r) tot += shist[r * 17 + tid];
    phist[blockIdx.x * BINS + tid] = tot;
  }
}

// ---------------- final feature assembly + MLP ----------------
__global__ __launch_bounds__(64) void k_final(const float* __restrict__ pg1, const float* __restrict__ pg2,
                                              const float* __restrict__ psum, const float* __restrict__ psumsq,
                                              const float* __restrict__ pmax, const int* __restrict__ phist,
                                              const float* __restrict__ w1, const float* __restrict__ b1,
                                              const float* __restrict__ w2, const float* __restrict__ b2,
                                              const float* __restrict__ w3, const float* __restrict__ b3,
                                              float* __restrict__ out) {
  __shared__ float f[FIN + 1];
  __shared__ float t1[64];
  __shared__ float t2[32];
  int g = blockIdx.x, t = threadIdx.x;
  {
    float s1v = 0.f, s2v = 0.f;
#pragma unroll
    for (int r = 0; r < 16; ++r) {
      s1v += pg1[(g * 16 + r) * 64 + t];
      s2v += pg2[(g * 16 + r) * 64 + t];
    }
    f[t]      = s1v * (1.f / NPG);
    f[64 + t] = s2v * (1.f / NPG);
  }
  if (t < BINS) {
    int tot = 0;
#pragma unroll
    for (int r = 0; r < 8; ++r) tot += phist[(g * 8 + r) * BINS + t];
    f[2 * H + t] = (float)tot * (1.f / 262144.f);
  }
  if (t == 0) {
    float s = 0.f, ss = 0.f, mx = -2.f;
#pragma unroll
    for (int r = 0; r < 8; ++r) {
      s += psum[g * 8 + r];
      ss += psumsq[g * 8 + r];
      mx = fmaxf(mx, pmax[g * 8 + r]);
    }
    const float inv = 1.f / 262144.f;
    float mean = s * inv;
    float var = fmaxf(ss * inv - mean * mean, 0.f);
    f[144] = mean;
    f[145] = mx;
    f[146] = sqrtf(var);
  }
  __syncthreads();
  float acc = b1[t];
  for (int k = 0; k < FIN; ++k) acc = fmaf(f[k], w1[k * 64 + t], acc);
  t1[t] = fmaxf(acc, 0.f);
  __syncthreads();
  if (t < 32) {
    float a2 = b2[t];
#pragma unroll 8
    for (int k = 0; k < 64; ++k) a2 = fmaf(t1[k], w2[k * 32 + t], a2);
    t2[t] = fmaxf(a2, 0.f);
  }
  __syncthreads();
  if (t == 0) {
    float a3 = b3[0];
#pragma unroll
    for (int k = 0; k < 32; ++k) a3 = fmaf(t2[k], w3[k], a3);
    out[g] = a3;
  }
}

}  // namespace

extern "C" void kernel_launch(void* const* d_in, const int* in_sizes, int n_in, void* d_out, int out_size,
                              void* d_ws, size_t ws_size, hipStream_t stream) {
  const float* x1 = (const float*)d_in[0];
  const int* e1 = (const int*)d_in[1];
  const float* x2 = (const float*)d_in[3];
  const int* e2 = (const int*)d_in[4];
  const float* enc_w1 = (const float*)d_in[6];
  const float* enc_b1 = (const float*)d_in[7];
  const float* enc_w2 = (const float*)d_in[8];
  const float* enc_b2 = (const float*)d_in[9];
  const float* enc_w3 = (const float*)d_in[10];
  const float* enc_b3 = (const float*)d_in[11];
  const float* enc_w4 = (const float*)d_in[12];
  const float* enc_b4 = (const float*)d_in[13];
  const float* mw1 = (const float*)d_in[14];
  const float* mb1 = (const float*)d_in[15];
  const float* mw2 = (const float*)d_in[16];
  const float* mb2 = (const float*)d_in[17];
  const float* mw3 = (const float*)d_in[18];
  const float* mb3 = (const float*)d_in[19];
  float* out = (float*)d_out;

  char* wsc = (char*)d_ws;
  size_t off = 0;
  auto alloc = [&](size_t bytes) -> void* {
    void* p = wsc + off;
    off += (bytes + 255) & ~(size_t)255;
    return p;
  };
  float* Hn = (float*)alloc((size_t)N2 * H * 4);          // 32 MB (normalized embeddings)
  __half* yH = (__half*)alloc((size_t)N2 * H * 2);        // 16 MB
  __half* tH = (__half*)alloc((size_t)N2 * H * 2);        // 16 MB (aliased as ebuf during CSR build)
  __half* zH = (__half*)alloc((size_t)N2 * H * 2);        // 16 MB
  __half* t2H = (__half*)alloc((size_t)N2 * H * 2);       // 16 MB
  int* rowptr = (int*)alloc((size_t)(N2 + 1) * 4);
  int* colidx = (int*)alloc((size_t)2 * E * 4);           // 8 MB
  int* bcnt = (int*)alloc((size_t)NSLICE * NBUCKET * 4);  // 1 MB
  int* boffs = (int*)alloc((size_t)NBUCKET * NSLICE * 4); // 1 MB
  int* tot = (int*)alloc((size_t)NBUCKET * 4);
  float* pg = (float*)alloc((size_t)(N2 / 32) * 64 * 4);  // 1 MB
  float* psum = (float*)alloc(1024 * 4);
  float* psumsq = (float*)alloc(1024 * 4);
  float* pmaxa = (float*)alloc(1024 * 4);
  int* phist = (int*)alloc((size_t)1024 * BINS * 4);
  (void)ws_size;
  (void)in_sizes;
  (void)n_in;
  (void)out_size;

  const int* src1 = e1;
  const int* dst1 = e1 + E;
  const int* src2 = e2;
  const int* dst2 = e2 + E;
  int* ebuf = (int*)tH;  // 8 MB; consumed by k_p6 before k_gather writes tH

  // CSR build (LDS-atomic bucket scheme) + xw co-scheduled; 0 global atomics
  k_p1_xw<<<NSLICE + N2 / 32, 256, 0, stream>>>(dst1, dst2, bcnt, x1, x2, enc_w1, yH);
  k_scanrows<<<NBUCKET, 256, 0, stream>>>(bcnt, boffs, tot);
  k_p5<<<NSLICE, 256, 0, stream>>>(src1, dst1, src2, dst2, boffs, tot, ebuf);
  k_p6<<<NBUCKET, 256, 0, stream>>>(ebuf, tot, rowptr, colidx);

  // encoder over 2N nodes (split kernels: gather = 2 nodes/wave for instruction efficiency + MLP)
  k_gather<<<N2 / 8, 256, 0, stream>>>(yH, rowptr, colidx, enc_b1, tH);
  k_mid<<<N2 / 32, 256, 0, stream>>>(tH, enc_w2, enc_b2, enc_w3, zH);
  k_gather<<<N2 / 8, 256, 0, stream>>>(zH, rowptr, colidx, enc_b3, t2H);
  k_last<<<N2 / 32, 256, 0, stream>>>(t2H, enc_w4, enc_b4, Hn, pg);

  k_sim<<<B * 8, 256, 0, stream>>>(Hn, psum, psumsq, pmaxa, phist);
  k_final<<<B, 64, 0, stream>>>(pg, pg + (size_t)2048 * 64, psum, psumsq, pmaxa, phist, mw1, mb1, mw2, mb2,
                                mw3, mb3, out);
}

// Round 9
// 325.728 us; speedup vs baseline: 1.4274x; 1.1415x over previous
//
#include <hip/hip_runtime.h>
#include <hip/hip_bf16.h>
#include <hip/hip_fp16.h>

namespace {

constexpr int N    = 65536;
constexpr int E    = 1048576;
constexpr int N2   = 2 * N;      // both sides concatenated
constexpr int B    = 128;
constexpr int NPG  = 512;
constexpr int IN   = 128;
constexpr int H    = 64;
constexpr int BINS = 16;
constexpr int FIN  = 2 * H + BINS + 3;  // 147
// CSR bucket scheme: 512 buckets of 256 dsts; 512 slices of 4096 edges.
constexpr int NBUCKET = 512;
constexpr int NSLICE  = 512;
constexpr int SLICE_E = 4096;

typedef _Float16 f16x8 __attribute__((ext_vector_type(8)));
typedef float f32x16 __attribute__((ext_vector_type(16)));

// ---------------- P1 (blocks 0..511): bucket histogram per slice, LDS only.
// ---------------- blocks 512..4607: y = x @ W1 -> fp16 (independent work, co-scheduled).

__global__ __launch_bounds__(256) void k_p1_xw(const int* __restrict__ dst1, const int* __restrict__ dst2,
                                               int* __restrict__ bcnt,
                                               const float* __restrict__ x1, const float* __restrict__ x2,
                                               const float* __restrict__ W, __half* __restrict__ y) {
  __shared__ float sW[IN * H];                     // 32 KB
  __shared__ __align__(16) float sx[4][IN][8];     // 16 KB
  __shared__ int hist[NBUCKET];                    // 2 KB
  int b = blockIdx.x, tid = threadIdx.x;
  if (b < NSLICE) {
    hist[tid] = 0;
    hist[tid + 256] = 0;
    __syncthreads();
    const int* d = (b < 256) ? dst1 : dst2;
    int ebase = (b & 255) * SLICE_E;
    int boff = (b < 256) ? 0 : 256;  // side2 dst+N -> bucket+256 (N = 256*256)
    for (int i = tid; i < SLICE_E; i += 256) atomicAdd(&hist[boff + (d[ebase + i] >> 8)], 1);
    __syncthreads();
    for (int k = tid; k < NBUCKET; k += 256) bcnt[b * NBUCKET + k] = hist[k];
  } else {
    int bx = b - NSLICE;
    int lane = tid & 63, sub = tid >> 6;
    for (int i = tid; i < IN * H; i += 256) sW[i] = W[i];
    __syncthreads();
    int nbase = bx * 32 + sub * 8;
    const float* xp = (nbase < N) ? (x1 + (size_t)nbase * IN) : (x2 + (size_t)(nbase - N) * IN);
#pragma unroll
    for (int nd = 0; nd < 8; ++nd) {
      const float* xr = xp + (size_t)nd * IN;
      sx[sub][lane][nd]      = xr[lane];
      sx[sub][lane + 64][nd] = xr[lane + 64];
    }
    // same-wave LDS producer/consumer: no barrier needed
    float acc[8];
#pragma unroll
    for (int nd = 0; nd < 8; ++nd) acc[nd] = 0.f;
    for (int k = 0; k < IN; ++k) {
      float wv = sW[k * H + lane];
      const float* p = &sx[sub][k][0];
      float4 lo = *(const float4*)(p);
      float4 hi = *(const float4*)(p + 4);
      acc[0] = fmaf(lo.x, wv, acc[0]); acc[1] = fmaf(lo.y, wv, acc[1]);
      acc[2] = fmaf(lo.z, wv, acc[2]); acc[3] = fmaf(lo.w, wv, acc[3]);
      acc[4] = fmaf(hi.x, wv, acc[4]); acc[5] = fmaf(hi.y, wv, acc[5]);
      acc[6] = fmaf(hi.z, wv, acc[6]); acc[7] = fmaf(hi.w, wv, acc[7]);
    }
#pragma unroll
    for (int nd = 0; nd < 8; ++nd) y[(size_t)(nbase + nd) * H + lane] = __float2half(acc[nd]);
  }
}

// P2: per-bucket exclusive scan across slices. boffs[bucket][slice]; tot[bucket].
__global__ __launch_bounds__(256) void k_scanrows(const int* __restrict__ bcnt, int* __restrict__ boffs,
                                                  int* __restrict__ tot) {
  __shared__ int s[NSLICE];
  int b = blockIdx.x, t = threadIdx.x;
  int v0 = bcnt[t * NBUCKET + b], v1 = bcnt[(t + 256) * NBUCKET + b];
  s[t] = v0;
  s[t + 256] = v1;
  __syncthreads();
  for (int d = 1; d < NSLICE; d <<= 1) {
    int a0 = (t >= d) ? s[t - d] : 0;
    int a1 = (t + 256 >= d) ? s[t + 256 - d] : 0;
    __syncthreads();
    s[t] += a0;
    s[t + 256] += a1;
    __syncthreads();
  }
  boffs[b * NSLICE + t] = s[t] - v0;
  boffs[b * NSLICE + t + 256] = s[t + 256] - v1;
  if (t == 255) tot[b] = s[NSLICE - 1];
}

// P5: scatter edges into bucket-grouped ebuf, packed (dstLow8 << 17) | src.
// LDS cursors only; bucket base scan recomputed in LDS (no extra launch).
__global__ __launch_bounds__(256) void k_p5(const int* __restrict__ src1, const int* __restrict__ dst1,
                                            const int* __restrict__ src2, const int* __restrict__ dst2,
                                            const int* __restrict__ boffs, const int* __restrict__ tot,
                                            int* __restrict__ ebuf) {
  __shared__ int stot[NBUCKET];
  __shared__ int sofs[NBUCKET];
  __shared__ int cur[NBUCKET];
  int b = blockIdx.x, tid = threadIdx.x;
  int v0 = tot[tid], v1 = tot[tid + 256];
  stot[tid] = v0;
  stot[tid + 256] = v1;
  __syncthreads();
  for (int d = 1; d < NBUCKET; d <<= 1) {
    int a0 = (tid >= d) ? stot[tid - d] : 0;
    int a1 = (tid + 256 >= d) ? stot[tid + 256 - d] : 0;
    __syncthreads();
    stot[tid] += a0;
    stot[tid + 256] += a1;
    __syncthreads();
  }
  sofs[tid]       = stot[tid] - v0 + boffs[tid * NSLICE + b];
  sofs[tid + 256] = stot[tid + 256] - v1 + boffs[(tid + 256) * NSLICE + b];
  cur[tid] = 0;
  cur[tid + 256] = 0;
  __syncthreads();
  const int* sr = (b < 256) ? src1 : src2;
  const int* d  = (b < 256) ? dst1 : dst2;
  int ebase = (b & 255) * SLICE_E;
  int off = (b < 256) ? 0 : N;
  int boff2 = (b < 256) ? 0 : 256;
  for (int i = tid; i < SLICE_E; i += 256) {
    int dd = d[ebase + i];
    int sv = off + sr[ebase + i];
    int bucket = boff2 + (dd >> 8);
    int r = atomicAdd(&cur[bucket], 1);
    ebuf[sofs[bucket] + r] = ((dd & 255) << 17) | sv;
  }
}

// P6: per-bucket CSR finalize (contiguous edge segment). LDS count+scan+scatter.
__global__ __launch_bounds__(256) void k_p6(const int* __restrict__ ebuf, const int* __restrict__ tot,
                                            int* __restrict__ rowptr, int* __restrict__ col) {
  __shared__ int stot[NBUCKET];
  __shared__ int c256[256];
  __shared__ int lofs[256];
  int b = blockIdx.x, t = threadIdx.x;
  {
    int v0 = tot[t], v1 = tot[t + 256];
    stot[t] = v0;
    stot[t + 256] = v1;
    __syncthreads();
    for (int d = 1; d < NBUCKET; d <<= 1) {
      int a0 = (t >= d) ? stot[t - d] : 0;
      int a1 = (t + 256 >= d) ? stot[t + 256 - d] : 0;
      __syncthreads();
      stot[t] += a0;
      stot[t + 256] += a1;
      __syncthreads();
    }
  }
  int e0 = (b == 0) ? 0 : stot[b - 1];
  int e1 = stot[b];
  c256[t] = 0;
  __syncthreads();
  for (int i = e0 + t; i < e1; i += 256) atomicAdd(&c256[(ebuf[i] >> 17) & 255], 1);
  __syncthreads();
  int v = c256[t];
  lofs[t] = v;
  __syncthreads();
  for (int d = 1; d < 256; d <<= 1) {
    int a = (t >= d) ? lofs[t - d] : 0;
    __syncthreads();
    lofs[t] += a;
    __syncthreads();
  }
  int excl = lofs[t] - v;
  rowptr[b * 256 + t] = e0 + excl;
  if (b == 0 && t == 0) rowptr[N2] = 2 * E;
  c256[t] = 0;
  lofs[t] = excl;
  __syncthreads();
  for (int i = e0 + t; i < e1; i += 256) {
    int pk = ebuf[i];
    int dl = (pk >> 17) & 255;
    int r = atomicAdd(&c256[dl], 1);
    col[e0 + lofs[dl] + r] = pk & 0x1FFFF;
  }
}

// ---------------- gather: out[n] = relu(in[n] + sum_{j->n} in[j] + bias), fp16 rows ----------------
// TWO nodes per wave (32 lanes each, __half2 loads): 32 independent row loads in flight per wave.

__global__ __launch_bounds__(256) void k_gather(const __half* __restrict__ in, const int* __restrict__ rowptr,
                                                const int* __restrict__ col, const float* __restrict__ bias,
                                                __half* __restrict__ outb) {
  int tid = threadIdx.x;
  int lane32 = tid & 31;
  int n = blockIdx.x * 8 + (tid >> 5);
  const __half2* in2 = (const __half2*)in;     // row = 32 half2
  __half2* out2 = (__half2*)outb;
  float2 bias2 = ((const float2*)bias)[lane32];
  int p0 = rowptr[n], p1 = rowptr[n + 1];
  __half2 self = in2[(size_t)n * 32 + lane32];
  float ax = __half2float(self.x) + bias2.x;
  float ay = __half2float(self.y) + bias2.y;
  int p = p0;
  for (; p + 16 <= p1; p += 16) {
    int myc = (lane32 < 16) ? col[p + lane32] : 0;
    __half2 v[16];
#pragma unroll
    for (int i = 0; i < 16; ++i) {
      int c = __shfl(myc, i, 32);
      v[i] = in2[(size_t)c * 32 + lane32];
    }
#pragma unroll
    for (int i = 0; i < 16; ++i) {
      ax += __half2float(v[i].x);
      ay += __half2float(v[i].y);
    }
  }
  if (p < p1) {
    int cnt = p1 - p;
    int myc = (lane32 < 16 && p + lane32 < p1) ? col[p + lane32] : 0;
#pragma unroll
    for (int i = 0; i < 16; ++i) {
      if (i < cnt) {
        int c = __shfl(myc, i, 32);
        __half2 v = in2[(size_t)c * 32 + lane32];
        ax += __half2float(v.x);
        ay += __half2float(v.y);
      }
    }
  }
  __half2 o;
  o.x = __float2half(fmaxf(ax, 0.f));
  o.y = __float2half(fmaxf(ay, 0.f));
  out2[(size_t)n * 32 + lane32] = o;
}

// ---------------- dense helpers ----------------

__device__ __forceinline__ void fma8(float (&acc)[8], const float* p, float wv) {
  float4 lo = *(const float4*)(p);
  float4 hi = *(const float4*)(p + 4);
  acc[0] = fmaf(lo.x, wv, acc[0]);
  acc[1] = fmaf(lo.y, wv, acc[1]);
  acc[2] = fmaf(lo.z, wv, acc[2]);
  acc[3] = fmaf(lo.w, wv, acc[3]);
  acc[4] = fmaf(hi.x, wv, acc[4]);
  acc[5] = fmaf(hi.y, wv, acc[5]);
  acc[6] = fmaf(hi.z, wv, acc[6]);
  acc[7] = fmaf(hi.w, wv, acc[7]);
}

// out = relu(in@Wa + ba) @ Wb    (fp16 in/out, f32 math)
__global__ __launch_bounds__(256) void k_mid(const __half* __restrict__ in, const float* __restrict__ Wa,
                                             const float* __restrict__ ba, const float* __restrict__ Wb,
                                             __half* __restrict__ outb) {
  __shared__ float sWa[H * H];
  __shared__ float sWb[H * H];
  __shared__ __align__(16) float st[4][H][8];
  int tid = threadIdx.x, lane = tid & 63, sub = tid >> 6;
  for (int i = tid; i < H * H; i += 256) sWa[i] = Wa[i];
  for (int i = tid; i < H * H; i += 256) sWb[i] = Wb[i];
  float biasA = ba[lane];
  __syncthreads();
  int nbase = blockIdx.x * 32 + sub * 8;
#pragma unroll
  for (int nd = 0; nd < 8; ++nd) st[sub][lane][nd] = __half2float(in[(size_t)(nbase + nd) * H + lane]);
  float acc[8];
#pragma unroll
  for (int nd = 0; nd < 8; ++nd) acc[nd] = biasA;
  for (int k = 0; k < H; ++k) fma8(acc, &st[sub][k][0], sWa[k * H + lane]);
#pragma unroll
  for (int nd = 0; nd < 8; ++nd) st[sub][lane][nd] = fmaxf(acc[nd], 0.f);
  float acc2[8];
#pragma unroll
  for (int nd = 0; nd < 8; ++nd) acc2[nd] = 0.f;
  for (int k = 0; k < H; ++k) fma8(acc2, &st[sub][k][0], sWb[k * H + lane]);
#pragma unroll
  for (int nd = 0; nd < 8; ++nd) outb[(size_t)(nbase + nd) * H + lane] = __float2half(acc2[nd]);
}

// h = relu(in@Wa + ba); write L2-normalized h (fp16) + per-32-node-tile pool partials (f32).
__global__ __launch_bounds__(256) void k_last(const __half* __restrict__ in, const float* __restrict__ Wa,
                                              const float* __restrict__ ba, __half* __restrict__ outn,
                                              float* __restrict__ pg) {
  __shared__ float sWa[H * H];
  __shared__ __align__(16) float st[4][H][8];
  __shared__ float sacc[4][64];
  int tid = threadIdx.x, lane = tid & 63, sub = tid >> 6;
  for (int i = tid; i < H * H; i += 256) sWa[i] = Wa[i];
  float biasA = ba[lane];
  __syncthreads();
  int nbase = blockIdx.x * 32 + sub * 8;
#pragma unroll
  for (int nd = 0; nd < 8; ++nd) st[sub][lane][nd] = __half2float(in[(size_t)(nbase + nd) * H + lane]);
  float acc[8];
#pragma unroll
  for (int nd = 0; nd < 8; ++nd) acc[nd] = biasA;
  for (int k = 0; k < H; ++k) fma8(acc, &st[sub][k][0], sWa[k * H + lane]);
  float psum = 0.f;
#pragma unroll
  for (int nd = 0; nd < 8; ++nd) {
    float h = fmaxf(acc[nd], 0.f);
    psum += h;
    float ss = h * h;
#pragma unroll
    for (int d = 1; d < 64; d <<= 1) ss += __shfl_xor(ss, d, 64);
    outn[(size_t)(nbase + nd) * H + lane] = __float2half(h / fmaxf(sqrtf(ss), 1e-12f));
  }
  sacc[sub][lane] = psum;
  __syncthreads();
  if (sub == 0) pg[blockIdx.x * 64 + lane] = sacc[0][lane] + sacc[1][lane] + sacc[2][lane] + sacc[3][lane];
}

// ---------------- fused sim + hist + stats via MFMA (fp16 inputs, f32 accum) ----------------
// Block = (graph g, 64-row tile rt of side1). 4 waves: wave w -> row-subtile (w&1)*32,
// col-tiles (w>>1)*8 .. +8 (each 32 cols). A fragments held in regs; B fragments loaded
// straight from L1/L2 (128KB/graph working set). No A/B LDS staging, no barriers in loop.
// NOTE: hist/mean/max/std are multiset-invariant => any consistent fragment-layout
// permutation is harmless; only A/B K-mapping inconsistency would corrupt values.
__global__ __launch_bounds__(256) void k_sim(const __half* __restrict__ Hn, float* __restrict__ psum,
                                             float* __restrict__ psumsq, float* __restrict__ pmax,
                                             int* __restrict__ phist) {
  __shared__ int shist[64 * 17];   // 64 replicas, stride 17
  __shared__ float sfin[4][4];
  int tid = threadIdx.x, lane = tid & 63, wv = tid >> 6;
  int g = blockIdx.x >> 3, rt = blockIdx.x & 7;
  for (int i = tid; i < 64 * 17; i += 256) shist[i] = 0;
  __syncthreads();

  int rtile = wv & 1;   // 32-row subtile within the 64-row block tile
  int cgrp  = wv >> 1;  // col-tile group: 8 tiles of 32 cols each
  int arow = lane & 31;
  int koff = (lane >> 5) * 8;  // K-half select (identical formula for A and B)

  const __half* H1 = Hn + ((size_t)g * NPG + rt * 64 + rtile * 32 + arow) * H + koff;
  f16x8 afrag[4];
#pragma unroll
  for (int kk = 0; kk < 4; ++kk) afrag[kk] = *(const f16x8*)(const void*)(H1 + kk * 16);

  const __half* H2g = Hn + ((size_t)N + (size_t)g * NPG + arow) * H + koff;
  float lmax = -2.f, lsum = 0.f, lsumsq = 0.f;
  int rep = lane * 17;
#pragma unroll 1
  for (int t = 0; t < 8; ++t) {
    int ct = cgrp * 8 + t;
    const __half* B0 = H2g + (size_t)(ct * 32) * H;
    f32x16 acc;
#pragma unroll
    for (int r = 0; r < 16; ++r) acc[r] = 0.f;
#pragma unroll
    for (int kk = 0; kk < 4; ++kk) {
      f16x8 bfrag = *(const f16x8*)(const void*)(B0 + kk * 16);
      acc = __builtin_amdgcn_mfma_f32_32x32x16_f16(afrag[kk], bfrag, acc, 0, 0, 0);
    }
#pragma unroll
    for (int r = 0; r < 16; ++r) {
      float v = acc[r];
      lmax = fmaxf(lmax, v);
      lsum += v;
      lsumsq = fmaf(v, v, lsumsq);
      int bin = (int)((v + 1.f) * 8.f);  // trunc==floor for v>=-1; clamp handles rest
      bin = bin < 0 ? 0 : (bin > BINS - 1 ? BINS - 1 : bin);
      atomicAdd(&shist[rep + bin], 1);
    }
  }
#pragma unroll
  for (int d = 1; d < 64; d <<= 1) {
    lsum += __shfl_xor(lsum, d, 64);
    lsumsq += __shfl_xor(lsumsq, d, 64);
    lmax = fmaxf(lmax, __shfl_xor(lmax, d, 64));
  }
  if (lane == 0) {
    sfin[wv][0] = lsum;
    sfin[wv][1] = lsumsq;
    sfin[wv][2] = lmax;
  }
  __syncthreads();
  if (tid == 0) {
    psum[blockIdx.x] = sfin[0][0] + sfin[1][0] + sfin[2][0] + sfin[3][0];
    psumsq[blockIdx.x] = sfin[0][1] + sfin[1][1] + sfin[2][1] + sfin[3][1];
    pmax[blockIdx.x] = fmaxf(fmaxf(sfin[0][2], sfin[1][2]), fmaxf(sfin[2][2], sfin[3][2]));
  }
  if (tid < BINS) {
    int tot = 0;
    for (int r = 0; r < 64; ++r) tot += shist[r * 17 + tid];
    phist[blockIdx.x * BINS + tid] = tot;
  }
}

// ---------------- final feature assembly + MLP ----------------
__global__ __launch_bounds__(64) void k_final(const float* __restrict__ pg1, const float* __restrict__ pg2,
                                              const float* __restrict__ psum, const float* __restrict__ psumsq,
                                              const float* __restrict__ pmax, const int* __restrict__ phist,
                                              const float* __restrict__ w1, const float* __restrict__ b1,
                                              const float* __restrict__ w2, const float* __restrict__ b2,
                                              const float* __restrict__ w3, const float* __restrict__ b3,
                                              float* __restrict__ out) {
  __shared__ float f[FIN + 1];
  __shared__ float t1[64];
  __shared__ float t2[32];
  int g = blockIdx.x, t = threadIdx.x;
  {
    float s1v = 0.f, s2v = 0.f;
#pragma unroll
    for (int r = 0; r < 16; ++r) {
      s1v += pg1[(g * 16 + r) * 64 + t];
      s2v += pg2[(g * 16 + r) * 64 + t];
    }
    f[t]      = s1v * (1.f / NPG);
    f[64 + t] = s2v * (1.f / NPG);
  }
  if (t < BINS) {
    int tot = 0;
#pragma unroll
    for (int r = 0; r < 8; ++r) tot += phist[(g * 8 + r) * BINS + t];
    f[2 * H + t] = (float)tot * (1.f / 262144.f);
  }
  if (t == 0) {
    float s = 0.f, ss = 0.f, mx = -2.f;
#pragma unroll
    for (int r = 0; r < 8; ++r) {
      s += psum[g * 8 + r];
      ss += psumsq[g * 8 + r];
      mx = fmaxf(mx, pmax[g * 8 + r]);
    }
    const float inv = 1.f / 262144.f;
    float mean = s * inv;
    float var = fmaxf(ss * inv - mean * mean, 0.f);
    f[144] = mean;
    f[145] = mx;
    f[146] = sqrtf(var);
  }
  __syncthreads();
  float acc = b1[t];
  for (int k = 0; k < FIN; ++k) acc = fmaf(f[k], w1[k * 64 + t], acc);
  t1[t] = fmaxf(acc, 0.f);
  __syncthreads();
  if (t < 32) {
    float a2 = b2[t];
#pragma unroll 8
    for (int k = 0; k < 64; ++k) a2 = fmaf(t1[k], w2[k * 32 + t], a2);
    t2[t] = fmaxf(a2, 0.f);
  }
  __syncthreads();
  if (t == 0) {
    float a3 = b3[0];
#pragma unroll
    for (int k = 0; k < 32; ++k) a3 = fmaf(t2[k], w3[k], a3);
    out[g] = a3;
  }
}

}  // namespace

extern "C" void kernel_launch(void* const* d_in, const int* in_sizes, int n_in, void* d_out, int out_size,
                              void* d_ws, size_t ws_size, hipStream_t stream) {
  const float* x1 = (const float*)d_in[0];
  const int* e1 = (const int*)d_in[1];
  const float* x2 = (const float*)d_in[3];
  const int* e2 = (const int*)d_in[4];
  const float* enc_w1 = (const float*)d_in[6];
  const float* enc_b1 = (const float*)d_in[7];
  const float* enc_w2 = (const float*)d_in[8];
  const float* enc_b2 = (const float*)d_in[9];
  const float* enc_w3 = (const float*)d_in[10];
  const float* enc_b3 = (const float*)d_in[11];
  const float* enc_w4 = (const float*)d_in[12];
  const float* enc_b4 = (const float*)d_in[13];
  const float* mw1 = (const float*)d_in[14];
  const float* mb1 = (const float*)d_in[15];
  const float* mw2 = (const float*)d_in[16];
  const float* mb2 = (const float*)d_in[17];
  const float* mw3 = (const float*)d_in[18];
  const float* mb3 = (const float*)d_in[19];
  float* out = (float*)d_out;

  char* wsc = (char*)d_ws;
  size_t off = 0;
  auto alloc = [&](size_t bytes) -> void* {
    void* p = wsc + off;
    off += (bytes + 255) & ~(size_t)255;
    return p;
  };
  __half* Hn = (__half*)alloc((size_t)N2 * H * 2);        // 16 MB (normalized embeddings, fp16)
  __half* yH = (__half*)alloc((size_t)N2 * H * 2);        // 16 MB
  __half* tH = (__half*)alloc((size_t)N2 * H * 2);        // 16 MB (aliased as ebuf during CSR build)
  __half* zH = (__half*)alloc((size_t)N2 * H * 2);        // 16 MB
  __half* t2H = (__half*)alloc((size_t)N2 * H * 2);       // 16 MB
  int* rowptr = (int*)alloc((size_t)(N2 + 1) * 4);
  int* colidx = (int*)alloc((size_t)2 * E * 4);           // 8 MB
  int* bcnt = (int*)alloc((size_t)NSLICE * NBUCKET * 4);  // 1 MB
  int* boffs = (int*)alloc((size_t)NBUCKET * NSLICE * 4); // 1 MB
  int* tot = (int*)alloc((size_t)NBUCKET * 4);
  float* pg = (float*)alloc((size_t)(N2 / 32) * 64 * 4);  // 1 MB
  float* psum = (float*)alloc(1024 * 4);
  float* psumsq = (float*)alloc(1024 * 4);
  float* pmaxa = (float*)alloc(1024 * 4);
  int* phist = (int*)alloc((size_t)1024 * BINS * 4);
  (void)ws_size;
  (void)in_sizes;
  (void)n_in;
  (void)out_size;

  const int* src1 = e1;
  const int* dst1 = e1 + E;
  const int* src2 = e2;
  const int* dst2 = e2 + E;
  int* ebuf = (int*)tH;  // 8 MB; consumed by k_p6 before k_gather writes tH

  // CSR build (LDS-atomic bucket scheme) + xw co-scheduled; 0 global atomics
  k_p1_xw<<<NSLICE + N2 / 32, 256, 0, stream>>>(dst1, dst2, bcnt, x1, x2, enc_w1, yH);
  k_scanrows<<<NBUCKET, 256, 0, stream>>>(bcnt, boffs, tot);
  k_p5<<<NSLICE, 256, 0, stream>>>(src1, dst1, src2, dst2, boffs, tot, ebuf);
  k_p6<<<NBUCKET, 256, 0, stream>>>(ebuf, tot, rowptr, colidx);

  // encoder over 2N nodes (split kernels: gather = 2 nodes/wave for instruction efficiency + MLP)
  k_gather<<<N2 / 8, 256, 0, stream>>>(yH, rowptr, colidx, enc_b1, tH);
  k_mid<<<N2 / 32, 256, 0, stream>>>(tH, enc_w2, enc_b2, enc_w3, zH);
  k_gather<<<N2 / 8, 256, 0, stream>>>(zH, rowptr, colidx, enc_b3, t2H);
  k_last<<<N2 / 32, 256, 0, stream>>>(t2H, enc_w4, enc_b4, Hn, pg);

  k_sim<<<B * 8, 256, 0, stream>>>(Hn, psum, psumsq, pmaxa, phist);
  k_final<<<B, 64, 0, stream>>>(pg, pg + (size_t)2048 * 64, psum, psumsq, pmaxa, phist, mw1, mb1, mw2, mb2,
                                mw3, mb3, out);
}